// Round 16
// baseline (206.044 us; speedup 1.0000x reference)
//
#include <hip/hip_runtime.h>
#include <math.h>

// ---------------- geometry ----------------
constexpr int N  = 167;          // field grid
constexpr int NN = 167 * 167;    // 27889
constexpr int NP = 90;           // input image
constexpr int MP = 84;           // pupil
constexpr int CROP = 120;
constexpr int HCOL = 84;         // Hermitian-reduced column count (t = 0..83)
constexpr int HALF_SZ = 1784896; // (16*167*167*8)/2  for threefry pairing

// ---------------- ws arena (float offsets) ----------------
constexpr size_t SZ_MAT   = (size_t)NN * 2;
constexpr size_t OFF_M1   = 0;
constexpr size_t OFF_M1T  = OFF_M1 + SZ_MAT;
constexpr size_t OFF_WF   = OFF_M1T + SZ_MAT;
constexpr size_t OFF_M2   = OFF_WF + SZ_MAT;
constexpr size_t OFF_M2T  = OFF_M2 + SZ_MAT;
constexpr size_t OFF_M3   = OFF_M2T + SZ_MAT;                  // [120][167] c
constexpr size_t OFF_M3T84= OFF_M3 + (size_t)CROP * N * 2;     // [84][120] c
constexpr size_t OFF_PHI2 = OFF_M3T84 + (size_t)HCOL * CROP * 2; // [167] c
constexpr size_t OFF_AMP  = OFF_PHI2 + (size_t)N * 2;
constexpr size_t OFF_X    = OFF_AMP + 4;                       // [16][167][84] c (16B-aligned)
constexpr size_t OFF_T1   = OFF_X  + (size_t)16 * N * HCOL * 2;// [16][167][90] c
constexpr size_t OFF_A    = OFF_T1 + (size_t)16 * N * NP * 2;  // [16][167][167] c
constexpr size_t OFF_T2   = OFF_A  + (size_t)16 * NN * 2;      // [16][167][84] c
constexpr size_t OFF_BD   = OFF_T2 + (size_t)16 * N * MP * 2;  // (unused now)
constexpr size_t OFF_T3   = OFF_BD + (size_t)8 * NN;           // [8][167][84] c
constexpr size_t OFF_OTF  = OFF_T3 + (size_t)8 * N * HCOL * 2; // [8][167][84] c
constexpr size_t OFF_FLAT = OFF_OTF+ (size_t)8 * N * HCOL * 2; // [16][12800]
constexpr size_t OFF_PC   = OFF_FLAT + (size_t)16 * 12800;     // [16][84][84] c
constexpr size_t WS_FLOATS = OFF_PC + (size_t)16 * MP * MP * 2;

// ---------------- helpers ----------------
__device__ __forceinline__ unsigned rotl32(unsigned x, int r) {
    return (x << r) | (x >> (32 - r));
}

// jax.random.normal(key(42), [16,167,167,8]) element at flat index idx
__device__ float noise_at(unsigned idx) {
    unsigned c0, c1; int lane;
    if (idx < (unsigned)HALF_SZ) { c0 = idx; c1 = idx + HALF_SZ; lane = 0; }
    else                         { c0 = idx - HALF_SZ; c1 = idx; lane = 1; }
    const unsigned ks0 = 0u, ks1 = 42u, ks2 = 0x1BD11BDAu ^ 42u;
    unsigned x0 = c0 + ks0, x1 = c1 + ks1;
#define TFR(r) { x0 += x1; x1 = rotl32(x1, r); x1 ^= x0; }
    TFR(13) TFR(15) TFR(26) TFR(6)   x0 += ks1; x1 += ks2 + 1u;
    TFR(17) TFR(29) TFR(16) TFR(24)  x0 += ks2; x1 += ks0 + 2u;
    TFR(13) TFR(15) TFR(26) TFR(6)   x0 += ks0; x1 += ks1 + 3u;
    TFR(17) TFR(29) TFR(16) TFR(24)  x0 += ks1; x1 += ks2 + 4u;
    TFR(13) TFR(15) TFR(26) TFR(6)   x0 += ks2; x1 += ks0 + 5u;
#undef TFR
    unsigned bits = lane ? x1 : x0;
    float u01 = __uint_as_float((bits >> 9) | 0x3F800000u) - 1.0f;
    const float lo = -0.99999994f;
    float f = fmaxf(lo, u01 * 2.0f + lo);
    float w = -log1pf(-f * f);
    float p;
    if (w < 5.0f) {
        w -= 2.5f;
        p = 2.81022636e-08f;
        p = fmaf(p, w, 3.43273939e-07f);
        p = fmaf(p, w, -3.5233877e-06f);
        p = fmaf(p, w, -4.39150654e-06f);
        p = fmaf(p, w, 0.00021858087f);
        p = fmaf(p, w, -0.00125372503f);
        p = fmaf(p, w, -0.00417768164f);
        p = fmaf(p, w, 0.246640727f);
        p = fmaf(p, w, 1.50140941f);
    } else {
        w = sqrtf(w) - 3.0f;
        p = -0.000200214257f;
        p = fmaf(p, w, 0.000100950558f);
        p = fmaf(p, w, 0.00134934322f);
        p = fmaf(p, w, -0.00367342844f);
        p = fmaf(p, w, 0.00573950773f);
        p = fmaf(p, w, -0.0076224613f);
        p = fmaf(p, w, 0.00943887047f);
        p = fmaf(p, w, 1.00167406f);
        p = fmaf(p, w, 2.83297682f);
    }
    return 1.41421356237f * p * f;
}

// ---------------- prep: DFT matrices (via omega table) + pupil field + disk area ----------------
__global__ void k_prep(const float* __restrict__ P, float* ws) {
    int bx = blockIdx.x, t = threadIdx.x;
    if (bx < 109) {
        __shared__ float2 wtab[N];   // wtab[s] = exp(+2pi i s/167) as (cos, sin)
        const float TPI = (float)(6.283185307179586476925286766559 / 167.0);
        for (int i = t; i < N; i += 256) {
            float s, c; sincosf(TPI * (float)i, &s, &c);
            wtab[i] = make_float2(c, s);
        }
        __syncthreads();
        int id = bx * 256 + t;
        if (id >= NN) return;
        int k = id / N, m = id % N;
        const float inv = 1.0f / 167.0f;
        int t1 = ((k + 84) * ((m + 83) % N)) % N;
        float2 w1 = wtab[t1];
        ws[OFF_M1 + 2 * id] = w1.x;  ws[OFF_M1 + 2 * id + 1] = -w1.y;
        ws[OFF_M1T + 2 * (m * N + k)] = w1.x;  ws[OFF_M1T + 2 * (m * N + k) + 1] = -w1.y;
        int tw = (k * m) % N;
        float2 ww = wtab[tw];
        ws[OFF_WF + 2 * id] = ww.x;  ws[OFF_WF + 2 * id + 1] = -ww.y;
        int t2 = ((k + 84) * m) % N;
        float2 w2 = wtab[t2];
        ws[OFF_M2 + 2 * id] = w2.x * inv;  ws[OFF_M2 + 2 * id + 1] = w2.y * inv;
        ws[OFF_M2T + 2 * (m * N + k)] = w2.x * inv;  ws[OFF_M2T + 2 * (m * N + k) + 1] = w2.y * inv;
        if (k < CROP) {
            int t3 = ((k + 108) * ((m + 83) % N)) % N;
            float2 w3 = wtab[t3];
            ws[OFF_M3 + 2 * (k * N + m)] = w3.x * inv;  ws[OFF_M3 + 2 * (k * N + m) + 1] = w3.y * inv;
            if (m < HCOL) {
                ws[OFF_M3T84 + 2 * (m * CROP + k)] = w3.x * inv;
                ws[OFF_M3T84 + 2 * (m * CROP + k) + 1] = w3.y * inv;
            }
        }
        if (id < N) {
            float2 wp = wtab[(2 * id) % N];
            ws[OFF_PHI2 + 2 * id] = wp.x;
            ws[OFF_PHI2 + 2 * id + 1] = wp.y;
        }
    } else if (bx < 550) {
        int id = (bx - 109) * 256 + t;
        if (id >= 16 * MP * MP) return;
        int rc = id % (MP * MP);
        int r = rc / MP, c = rc % MP;
        float y = r - 41.5f, x = c - 41.5f;
        float2 v = {0.f, 0.f};
        if (x * x + y * y <= 1764.0f) {
            float sp, cp; sincosf(P[id], &sp, &cp);
            v.x = cp; v.y = sp;
        }
        ((float2*)(ws + OFF_PC))[id] = v;
    } else {
        __shared__ int red[256];
        int cnt = 0;
        for (int i = t; i < MP * MP; i += 256) {
            int r = i / MP, c = i % MP;
            float y = r - 41.5f, x = c - 41.5f;
            if (x * x + y * y <= 1764.0f) cnt++;
        }
        red[t] = cnt; __syncthreads();
        for (int s = 128; s > 0; s >>= 1) { if (t < s) red[t] += red[t + s]; __syncthreads(); }
        if (t == 0) ws[OFF_AMP] = (float)red[0];
    }
}

// ---------------- row transforms: T1 = M1 * xpad  |  T2 = F * Pc ----------------
__global__ __launch_bounds__(128) void k_rows(const float* __restrict__ x, float* ws) {
    int kr = blockIdx.x, bj = blockIdx.y, t = threadIdx.x;
    __shared__ float2 wbuf[NP];
    if (blockIdx.z == 0) {
        const float2* M1 = (const float2*)(ws + OFF_M1);
        if (t < NP) wbuf[t] = M1[kr * N + 39 + t];
        __syncthreads();
        if (t >= NP) return;
        float2 acc = {0.f, 0.f};
        for (int nr = 0; nr < NP; nr++) {
            float2 w = wbuf[nr];
            float xv = x[(bj * NP + nr) * NP + t];
            acc.x += w.x * xv; acc.y += w.y * xv;
        }
        ((float2*)(ws + OFF_T1))[(bj * N + kr) * NP + t] = acc;
    } else {
        const float2* WF = (const float2*)(ws + OFF_WF);
        if (t < MP) wbuf[t] = WF[kr * N + 42 + t];
        __syncthreads();
        if (t >= MP) return;
        const float2* PC = (const float2*)(ws + OFF_PC) + (size_t)bj * MP * MP;
        float2 acc = {0.f, 0.f};
        for (int nr = 0; nr < MP; nr++) {
            float2 w = wbuf[nr];
            float2 pc = PC[nr * MP + t];
            acc.x += w.x * pc.x - w.y * pc.y;
            acc.y += w.x * pc.y + w.y * pc.x;
        }
        ((float2*)(ws + OFF_T2))[(bj * N + kr) * MP + t] = acc;
    }
}

// ---------------- col transforms: X (Hermitian-halved) | A (full), b128 LDS reads ----------------
constexpr int RCH = 6;
__global__ __launch_bounds__(192) void k_cols(float* ws) {
    int bj = blockIdx.y, tid = threadIdx.x;
    __shared__ __align__(16) float2 sbuf[RCH * MP];   // 504 float2, covers both uses
    if (blockIdx.x < 84) {
        // ---- X[:,0..83] = T1 * M1^T, 2 rows/block ----
        int k0 = blockIdx.x * 2;
        const float2* T1 = (const float2*)(ws + OFF_T1);
        for (int idx = tid; idx < 2 * NP; idx += 192) {
            int r = idx / NP, m = idx % NP;
            if (k0 + r < N) sbuf[r * NP + m] = T1[((size_t)bj * N + k0 + r) * NP + m];
        }
        __syncthreads();
        int col = tid % HCOL, grp = tid / HCOL;
        if (grp >= 2) return;
        int kr = k0 + grp;
        if (kr >= N) return;
        const float2* M1T = (const float2*)(ws + OFF_M1T);
        float2 acc = {0.f, 0.f};
#pragma unroll 5
        for (int ncp = 0; ncp < 45; ncp++) {       // NP = 90 = 45 pairs
            int nc = 2 * ncp;
            float4 u = *(const float4*)&sbuf[grp * NP + nc];
            float2 w0 = M1T[(39 + nc) * N + col];
            float2 w1 = M1T[(40 + nc) * N + col];
            acc.x += u.x * w0.x - u.y * w0.y;
            acc.y += u.x * w0.y + u.y * w0.x;
            acc.x += u.z * w1.x - u.w * w1.y;
            acc.y += u.z * w1.y + u.w * w1.x;
        }
        ((float2*)(ws + OFF_X))[((size_t)bj * N + kr) * HCOL + col] = acc;
    } else {
        // ---- A = T2 * F^T, 6 rows/block, full 167 cols ----
        int i0 = (blockIdx.x - 84) * RCH;
        const float2* T2 = (const float2*)(ws + OFF_T2);
        for (int idx = tid; idx < RCH * MP; idx += 192) {
            int q = idx / MP, nc = idx % MP, kr = i0 + q;
            if (kr < N) sbuf[idx] = T2[(bj * N + kr) * MP + nc];
        }
        __syncthreads();
        if (tid >= N) return;
        const float2* WF = (const float2*)(ws + OFF_WF);
        float2 acc[RCH];
#pragma unroll
        for (int q = 0; q < RCH; q++) acc[q] = make_float2(0.f, 0.f);
        for (int ncp = 0; ncp < 42; ncp++) {       // MP = 84 = 42 pairs
            int nc = 2 * ncp;
            float2 w0 = WF[(42 + nc) * N + tid];
            float2 w1 = WF[(43 + nc) * N + tid];
#pragma unroll
            for (int q = 0; q < RCH; q++) {
                float4 u = *(const float4*)&sbuf[q * MP + nc];
                acc[q].x += u.x * w0.x - u.y * w0.y;
                acc[q].y += u.x * w0.y + u.y * w0.x;
                acc[q].x += u.z * w1.x - u.w * w1.y;
                acc[q].y += u.z * w1.y + u.w * w1.x;
            }
        }
        float2* A = (float2*)(ws + OFF_A);
#pragma unroll
        for (int q = 0; q < RCH; q++)
            if (i0 + q < N) A[((size_t)bj * N + i0 + q) * N + tid] = acc[q];
    }
}

// ---------------- stage 2c: T3[k, 0..83] = sum_m Bd[k,m] * M2T[m,t], Bd inline ----------------
__global__ __launch_bounds__(192) void k2c(float* ws) {
    int chunk = blockIdx.x, c = blockIdx.y, tid = threadIdx.x;
    int k0 = chunk * 2;
    __shared__ float bds[2][N];
    const float2* A = (const float2*)(ws + OFF_A);
    float inv_amp = 1.0f / ws[OFF_AMP];
    for (int idx = tid; idx < 2 * N; idx += 192) {
        int r = idx / N, m = idx % N;
        int k = k0 + r;
        if (k < N) {
            float2 a0 = A[((size_t)c * N + k) * N + m];
            float2 a1 = A[((size_t)(c + 8) * N + k) * N + m];
            bds[r][m] = (a0.x * a0.x + a0.y * a0.y - a1.x * a1.x - a1.y * a1.y) * inv_amp;
        }
    }
    __syncthreads();
    int col = tid % HCOL, grp = tid / HCOL;
    if (grp >= 2) return;
    int k = k0 + grp;
    if (k >= N) return;
    const float2* M2T = (const float2*)(ws + OFF_M2T);
    float2 acc = {0.f, 0.f};
    for (int m = 0; m < N; m++) {
        float bv = bds[grp][m];
        float2 w = M2T[m * N + col];
        acc.x += w.x * bv; acc.y += w.y * bv;
    }
    ((float2*)(ws + OFF_T3))[((size_t)c * N + k) * HCOL + col] = acc;
}

// ---------------- stage 2d: OTF[i, 0..83] = sum_k M2[i,k] * T3[k,t] ----------------
__global__ __launch_bounds__(192) void k2d(float* ws) {
    int chunk = blockIdx.x, c = blockIdx.y, tid = threadIdx.x;
    int i0 = chunk * 2;
    __shared__ float2 m2s[2][N];
    const float2* M2 = (const float2*)(ws + OFF_M2);
    for (int idx = tid; idx < 2 * N; idx += 192) {
        int r = idx / N, k = idx % N;
        if (i0 + r < N) m2s[r][k] = M2[(i0 + r) * N + k];
    }
    __syncthreads();
    int col = tid % HCOL, grp = tid / HCOL;
    if (grp >= 2) return;
    int i = i0 + grp;
    if (i >= N) return;
    const float2* T3 = (const float2*)(ws + OFF_T3) + (size_t)c * N * HCOL;
    float2 acc = {0.f, 0.f};
    for (int k = 0; k < N; k++) {
        float2 w = m2s[grp][k];
        float2 u = T3[k * HCOL + col];
        acc.x += u.x * w.x - u.y * w.y;
        acc.y += u.x * w.y + u.y * w.x;
    }
    ((float2*)(ws + OFF_OTF))[((size_t)c * N + i) * HCOL + col] = acc;
}

// ---------------- stage 3 fused: 12 rows/block, dbuf, KCH=12 (VGPR<=64, LDS 21.7KB) ----------------
constexpr int K34R = 12;   // rows per block (4 pool rows)
constexpr int KCH  = 12;   // kr chunk staged per iteration
constexpr int NT34 = (N + KCH - 1) / KCH;   // 14 (13 full + 1 tail of 11)

constexpr int SM_ZS   = 0;
constexpr int SM_M3C  = SM_ZS + 2 * KCH * HCOL * 2;      // 4032
constexpr int SM_PHIS = SM_M3C + 2 * KCH * K34R * 2;     // 4608
constexpr int SM_PM   = SM_PHIS + N * 2;                 // 4942
constexpr int SM_TOT  = SM_PM + 4 * CROP;                // 5422 floats = 21688 B

constexpr int ZBUF = KCH * HCOL;    // float2 elements per zs buffer (1008)
constexpr int MBUF = KCH * K34R;    // float2 elements per m3c buffer (144)

#define K34_FMA_BODY(kl)                                                        \
    {                                                                           \
        float4 zz = *(const float4*)&zcur[(kl) * HCOL + 2 * pair];              \
        float4 wa = *(const float4*)&mcur[(kl) * K34R + r0];                    \
        a00.x += wa.x * zz.x - wa.y * zz.y;  a00.y += wa.x * zz.y + wa.y * zz.x;\
        a01.x += wa.x * zz.z - wa.y * zz.w;  a01.y += wa.x * zz.w + wa.y * zz.z;\
        a10.x += wa.z * zz.x - wa.w * zz.y;  a10.y += wa.z * zz.y + wa.w * zz.x;\
        a11.x += wa.z * zz.z - wa.w * zz.w;  a11.y += wa.z * zz.w + wa.w * zz.z;\
    }

__global__ __launch_bounds__(256) void k34(float* ws) {
    int chunk = blockIdx.x, c = blockIdx.y, b = blockIdx.z, tid = threadIdx.x;
    int i0 = chunk * K34R;
    __shared__ __align__(16) float smem[SM_TOT];
    float2* zbase = (float2*)(smem + SM_ZS);
    float2* mbase = (float2*)(smem + SM_M3C);
    float2* phis  = (float2*)(smem + SM_PHIS);
    float*  pmf   = smem + SM_PM;                            // pm[4][CROP] flat
    float2 (*us)[HCOL] = (float2 (*)[HCOL])(smem + SM_ZS);   // alias: zs dead after loop

    const float2* M3 = (const float2*)(ws + OFF_M3);
    const float4* X4   = (const float4*)(ws + OFF_X   + (size_t)b * N * HCOL * 2);
    const float4* OTF4 = (const float4*)(ws + OFF_OTF + (size_t)c * N * HCOL * 2);
    for (int idx = tid; idx < N; idx += 256) phis[idx] = ((const float2*)(ws + OFF_PHI2))[idx];

    // staging coords: float4 = 2 cols; 42 quads/row; 504 quads per full chunk, 2/thread
    int qkl[2], qcp[2];
#pragma unroll
    for (int e = 0; e < 2; e++) {
        int idx = tid + e * 256;
        qkl[e] = idx / 42; qcp[e] = idx - qkl[e] * 42;   // qkl<12 valid
    }
    int mkl = tid % 12, mr = tid / 12;   // tid<144: m3c coords (kl 0..11, r 0..11)

    int pair = tid % 42, grp = tid / 42;   // grp<6: 2 rows x 2 cols per thread
    int r0 = grp * 2;
    float2 a00 = {0.f,0.f}, a01 = {0.f,0.f}, a10 = {0.f,0.f}, a11 = {0.f,0.f};

    float4 xq[2], oq[2];
    float2 m3r;

    // ---- prologue: load chunk 0, write LDS buf 0 ----
#pragma unroll
    for (int e = 0; e < 2; e++)
        if (qkl[e] < KCH) { xq[e] = X4[qkl[e] * 42 + qcp[e]]; oq[e] = OTF4[qkl[e] * 42 + qcp[e]]; }
    if (tid < 144) m3r = M3[(i0 + mr) * N + mkl];
#pragma unroll
    for (int e = 0; e < 2; e++)
        if (qkl[e] < KCH) {
            float4 z;
            z.x = xq[e].x * oq[e].x - xq[e].y * oq[e].y;
            z.y = xq[e].x * oq[e].y + xq[e].y * oq[e].x;
            z.z = xq[e].z * oq[e].z - xq[e].w * oq[e].w;
            z.w = xq[e].z * oq[e].w + xq[e].w * oq[e].z;
            *(float4*)&zbase[qkl[e] * HCOL + 2 * qcp[e]] = z;
        }
    if (tid < 144) mbase[mkl * K34R + mr] = m3r;
    __syncthreads();

    // ---- main loop: prefetch(t+1) -> FMA(t) on cbuf (nbuf writes interleave) -> barrier ----
    for (int t = 0; t < NT34; t++) {
        int cbuf = t & 1, nbuf = cbuf ^ 1;
        int kr0 = t * KCH;
        int chn = min(KCH, N - kr0);
        int nbase = kr0 + KCH;
        int nchn = (t + 1 < NT34) ? (N - nbase < KCH ? N - nbase : KCH) : 0;
        if (nchn > 0) {
#pragma unroll
            for (int e = 0; e < 2; e++)
                if (qkl[e] < nchn) { xq[e] = X4[(nbase + qkl[e]) * 42 + qcp[e]];
                                     oq[e] = OTF4[(nbase + qkl[e]) * 42 + qcp[e]]; }
            if (tid < 144 && mkl < nchn) m3r = M3[(i0 + mr) * N + nbase + mkl];
        }
        const float2* zcur = zbase + cbuf * ZBUF;
        const float2* mcur = mbase + cbuf * MBUF;
        if (grp < 6) {
            if (chn == KCH) {
#pragma unroll
                for (int kl = 0; kl < KCH; kl++) K34_FMA_BODY(kl)
            } else {
#pragma unroll
                for (int kl = 0; kl < KCH - 1; kl++) K34_FMA_BODY(kl)   // tail chn = 11
            }
        }
        if (nchn > 0) {
            float2* znxt = zbase + nbuf * ZBUF;
            float2* mnxt = mbase + nbuf * MBUF;
#pragma unroll
            for (int e = 0; e < 2; e++)
                if (qkl[e] < nchn) {
                    float4 z;
                    z.x = xq[e].x * oq[e].x - xq[e].y * oq[e].y;
                    z.y = xq[e].x * oq[e].y + xq[e].y * oq[e].x;
                    z.z = xq[e].z * oq[e].z - xq[e].w * oq[e].w;
                    z.w = xq[e].z * oq[e].w + xq[e].w * oq[e].z;
                    *(float4*)&znxt[qkl[e] * HCOL + 2 * qcp[e]] = z;
                }
            if (tid < 144 && mkl < nchn) mnxt[mkl * K34R + mr] = m3r;
        }
        __syncthreads();
    }

    // ---- write U rows (us aliases zs; all zs reads completed before last barrier) ----
    if (grp < 6) {
        *(float4*)&us[r0][2 * pair]     = make_float4(a00.x, a00.y, a01.x, a01.y);
        *(float4*)&us[r0 + 1][2 * pair] = make_float4(a10.x, a10.y, a11.x, a11.y);
    }
    __syncthreads();

    // ---- phase 2: j-transform + phase fixup + noise + relu + 3-row max ----
    if (tid < 240) {
        int grp2 = tid / CROP, j = tid % CROP;
        int rbase = grp2 * 6;
        const float2* M3T84 = (const float2*)(ws + OFF_M3T84);
        float2 A[6]; float Bq[6];
#pragma unroll
        for (int q = 0; q < 6; q++) A[q] = make_float2(0.f, 0.f);
#pragma unroll 4
        for (int ncp = 0; ncp < 41; ncp++) {
            int nc = 2 * ncp;
            float2 w0 = M3T84[nc * CROP + j];
            float2 w1 = M3T84[(nc + 1) * CROP + j];
#pragma unroll
            for (int q = 0; q < 6; q++) {
                float4 u = *(const float4*)&us[rbase + q][nc];
                A[q].x += u.x * w0.x - u.y * w0.y;
                A[q].y += u.x * w0.y + u.y * w0.x;
                A[q].x += u.z * w1.x - u.w * w1.y;
                A[q].y += u.z * w1.y + u.w * w1.x;
            }
        }
        {   // nc = 82 singleton
            float2 w = M3T84[82 * CROP + j];
#pragma unroll
            for (int q = 0; q < 6; q++) {
                float2 u = us[rbase + q][82];
                A[q].x += u.x * w.x - u.y * w.y;
                A[q].y += u.x * w.y + u.y * w.x;
            }
        }
        {   // B term: nc = 83 (self-paired column), real part only
            float2 w = M3T84[(HCOL - 1) * CROP + j];
#pragma unroll
            for (int q = 0; q < 6; q++) {
                float2 u = us[rbase + q][HCOL - 1];
                Bq[q] = u.x * w.x - u.y * w.y;
            }
        }
#pragma unroll
        for (int g = 0; g < 2; g++) {
            float vmax = 0.f;  // relu folded in
#pragma unroll
            for (int r = 0; r < 3; r++) {
                int q = g * 3 + r, i = i0 + rbase + q;
                int s = i + j + 49; if (s >= N) s -= N;   // (i+j+216) mod 167
                float2 ph = phis[s];
                float val = A[q].x * (1.0f + ph.x) - A[q].y * ph.y + Bq[q];
                unsigned idx = (((unsigned)b * N + (24 + i)) * N + (24 + j)) * 8u + c;
                val += 0.003f * noise_at(idx);
                vmax = fmaxf(vmax, val);
            }
            pmf[(grp2 * 2 + g) * CROP + j] = vmax;
        }
    }
    __syncthreads();
    if (tid < 160) {
        int pr = tid / 40, pc = tid % 40;
        float m = fmaxf(fmaxf(pmf[pr * CROP + 3 * pc], pmf[pr * CROP + 3 * pc + 1]),
                        pmf[pr * CROP + 3 * pc + 2]);
        int prow = chunk * 4 + pr;
        ws[OFF_FLAT + (size_t)b * 12800 + ((size_t)prow * 40 + pc) * 8 + c] = m;
    }
}

// ---------------- stage 4: dense(12800->10) + softmax ----------------
__global__ void k5(const float* __restrict__ W3, const float* __restrict__ b3,
                   const float* __restrict__ ws, float* __restrict__ out) {
    int b = blockIdx.x, t = threadIdx.x;
    __shared__ float red[256][10];
    float acc[10];
#pragma unroll
    for (int o = 0; o < 10; o++) acc[o] = 0.f;
    const float* fl = ws + OFF_FLAT + (size_t)b * 12800;
    for (int f = t; f < 12800; f += 256) {
        float v = fl[f];
#pragma unroll
        for (int o = 0; o < 10; o++) acc[o] = fmaf(v, W3[f * 10 + o], acc[o]);
    }
#pragma unroll
    for (int o = 0; o < 10; o++) red[t][o] = acc[o];
    __syncthreads();
    for (int s = 128; s > 0; s >>= 1) {
        if (t < s) {
#pragma unroll
            for (int o = 0; o < 10; o++) red[t][o] += red[t + s][o];
        }
        __syncthreads();
    }
    if (t == 0) {
        float lg[10], mx = -1e30f;
#pragma unroll
        for (int o = 0; o < 10; o++) { lg[o] = red[0][o] + b3[o]; mx = fmaxf(mx, lg[o]); }
        float sum = 0.f;
#pragma unroll
        for (int o = 0; o < 10; o++) { lg[o] = expf(lg[o] - mx); sum += lg[o]; }
#pragma unroll
        for (int o = 0; o < 10; o++) out[b * 10 + o] = lg[o] / sum;
    }
}

extern "C" void kernel_launch(void* const* d_in, const int* in_sizes, int n_in,
                              void* d_out, int out_size, void* d_ws, size_t ws_size,
                              hipStream_t stream) {
    const float* x  = (const float*)d_in[0];   // [16,90,90,1]
    const float* P  = (const float*)d_in[1];   // [16,84,84]
    const float* W3 = (const float*)d_in[2];   // [12800,10]
    const float* b3 = (const float*)d_in[3];   // [10]
    float* ws  = (float*)d_ws;
    float* out = (float*)d_out;                // [16,10]

    k_prep<<<551, 256, 0, stream>>>(P, ws);
    k_rows<<<dim3(N, 16, 2), 128, 0, stream>>>(x, ws);
    k_cols<<<dim3(84 + 28, 16), 192, 0, stream>>>(ws);
    k2c<<<dim3(84, 8), 192, 0, stream>>>(ws);
    k2d<<<dim3(84, 8), 192, 0, stream>>>(ws);
    k34<<<dim3(CROP / K34R, 8, 16), 256, 0, stream>>>(ws);
    k5<<<16, 256, 0, stream>>>(W3, b3, ws, out);
}

// Round 17
// 199.531 us; speedup vs baseline: 1.0326x; 1.0326x over previous
//
#include <hip/hip_runtime.h>
#include <math.h>

// ---------------- geometry ----------------
constexpr int N  = 167;          // field grid
constexpr int NN = 167 * 167;    // 27889
constexpr int NP = 90;           // input image
constexpr int MP = 84;           // pupil
constexpr int CROP = 120;
constexpr int HCOL = 84;         // Hermitian-reduced column count (t = 0..83)
constexpr int HALF_SZ = 1784896; // (16*167*167*8)/2  for threefry pairing

// ---------------- ws arena (float offsets) ----------------
constexpr size_t SZ_MAT   = (size_t)NN * 2;
constexpr size_t OFF_M1   = 0;
constexpr size_t OFF_M1T  = OFF_M1 + SZ_MAT;
constexpr size_t OFF_WF   = OFF_M1T + SZ_MAT;
constexpr size_t OFF_M2   = OFF_WF + SZ_MAT;                   // (unused, kept for layout)
constexpr size_t OFF_M2T  = OFF_M2 + SZ_MAT;
constexpr size_t OFF_M3   = OFF_M2T + SZ_MAT;                  // [120][167] c
constexpr size_t OFF_M3T84= OFF_M3 + (size_t)CROP * N * 2;     // [84][120] c
constexpr size_t OFF_PHI2 = OFF_M3T84 + (size_t)HCOL * CROP * 2; // [167] c
constexpr size_t OFF_AMP  = OFF_PHI2 + (size_t)N * 2;
constexpr size_t OFF_X    = OFF_AMP + 4;                       // [16][167][84] c (16B-aligned)
constexpr size_t OFF_T1   = OFF_X  + (size_t)16 * N * HCOL * 2;// (unused)
constexpr size_t OFF_A    = OFF_T1 + (size_t)16 * N * NP * 2;  // (unused)
constexpr size_t OFF_T2   = OFF_A  + (size_t)16 * NN * 2;      // (unused)
constexpr size_t OFF_BD   = OFF_T2 + (size_t)16 * N * MP * 2;  // (unused)
constexpr size_t OFF_T3   = OFF_BD + (size_t)8 * NN;           // [8][167][84] c
constexpr size_t OFF_OTF  = OFF_T3 + (size_t)8 * N * HCOL * 2; // [8][167][84] c
constexpr size_t OFF_FLAT = OFF_OTF+ (size_t)8 * N * HCOL * 2; // [16][12800]
constexpr size_t OFF_PC   = OFF_FLAT + (size_t)16 * 12800;     // [16][84][84] c
constexpr size_t WS_FLOATS = OFF_PC + (size_t)16 * MP * MP * 2;

// ---------------- helpers ----------------
__device__ __forceinline__ unsigned rotl32(unsigned x, int r) {
    return (x << r) | (x >> (32 - r));
}

// jax.random.normal(key(42), [16,167,167,8]) element at flat index idx
__device__ float noise_at(unsigned idx) {
    unsigned c0, c1; int lane;
    if (idx < (unsigned)HALF_SZ) { c0 = idx; c1 = idx + HALF_SZ; lane = 0; }
    else                         { c0 = idx - HALF_SZ; c1 = idx; lane = 1; }
    const unsigned ks0 = 0u, ks1 = 42u, ks2 = 0x1BD11BDAu ^ 42u;
    unsigned x0 = c0 + ks0, x1 = c1 + ks1;
#define TFR(r) { x0 += x1; x1 = rotl32(x1, r); x1 ^= x0; }
    TFR(13) TFR(15) TFR(26) TFR(6)   x0 += ks1; x1 += ks2 + 1u;
    TFR(17) TFR(29) TFR(16) TFR(24)  x0 += ks2; x1 += ks0 + 2u;
    TFR(13) TFR(15) TFR(26) TFR(6)   x0 += ks0; x1 += ks1 + 3u;
    TFR(17) TFR(29) TFR(16) TFR(24)  x0 += ks1; x1 += ks2 + 4u;
    TFR(13) TFR(15) TFR(26) TFR(6)   x0 += ks2; x1 += ks0 + 5u;
#undef TFR
    unsigned bits = lane ? x1 : x0;
    float u01 = __uint_as_float((bits >> 9) | 0x3F800000u) - 1.0f;
    const float lo = -0.99999994f;
    float f = fmaxf(lo, u01 * 2.0f + lo);
    float w = -log1pf(-f * f);
    float p;
    if (w < 5.0f) {
        w -= 2.5f;
        p = 2.81022636e-08f;
        p = fmaf(p, w, 3.43273939e-07f);
        p = fmaf(p, w, -3.5233877e-06f);
        p = fmaf(p, w, -4.39150654e-06f);
        p = fmaf(p, w, 0.00021858087f);
        p = fmaf(p, w, -0.00125372503f);
        p = fmaf(p, w, -0.00417768164f);
        p = fmaf(p, w, 0.246640727f);
        p = fmaf(p, w, 1.50140941f);
    } else {
        w = sqrtf(w) - 3.0f;
        p = -0.000200214257f;
        p = fmaf(p, w, 0.000100950558f);
        p = fmaf(p, w, 0.00134934322f);
        p = fmaf(p, w, -0.00367342844f);
        p = fmaf(p, w, 0.00573950773f);
        p = fmaf(p, w, -0.0076224613f);
        p = fmaf(p, w, 0.00943887047f);
        p = fmaf(p, w, 1.00167406f);
        p = fmaf(p, w, 2.83297682f);
    }
    return 1.41421356237f * p * f;
}

// ---------------- prep: DFT matrices (all layouts written COALESCED) + pupil + amp ----------------
__global__ void k_prep(const float* __restrict__ P, float* ws) {
    int bx = blockIdx.x, t = threadIdx.x;
    if (bx < 258) {
        __shared__ float2 wtab[N];   // wtab[s] = exp(+2pi i s/167)
        const float TPI = (float)(6.283185307179586476925286766559 / 167.0);
        for (int i = t; i < N; i += 256) {
            float s, c; sincosf(TPI * (float)i, &s, &c);
            wtab[i] = make_float2(c, s);
        }
        __syncthreads();
        const float inv = 1.0f / 167.0f;
        if (bx < 109) {
            // row-major layouts: id = k*N + m
            int id = bx * 256 + t;
            if (id >= NN) return;
            int k = id / N, m = id % N;
            int t1 = ((k + 84) * ((m + 83) % N)) % N;
            float2 w1 = wtab[t1];
            ws[OFF_M1 + 2 * id] = w1.x;  ws[OFF_M1 + 2 * id + 1] = -w1.y;
            int tw = (k * m) % N;
            float2 ww = wtab[tw];
            ws[OFF_WF + 2 * id] = ww.x;  ws[OFF_WF + 2 * id + 1] = -ww.y;
            if (k < CROP) {
                int t3 = ((k + 108) * ((m + 83) % N)) % N;
                float2 w3 = wtab[t3];
                ws[OFF_M3 + 2 * (k * N + m)] = w3.x * inv;
                ws[OFF_M3 + 2 * (k * N + m) + 1] = w3.y * inv;
            }
            if (id < N) {
                float2 wp = wtab[(2 * id) % N];
                ws[OFF_PHI2 + 2 * id] = wp.x;
                ws[OFF_PHI2 + 2 * id + 1] = wp.y;
            }
        } else if (bx < 218) {
            // transposed layouts: id = m*N + k  (coalesced store, recomputed index)
            int id = (bx - 109) * 256 + t;
            if (id >= NN) return;
            int m = id / N, k = id % N;
            int t1 = ((k + 84) * ((m + 83) % N)) % N;
            float2 w1 = wtab[t1];
            ws[OFF_M1T + 2 * id] = w1.x;  ws[OFF_M1T + 2 * id + 1] = -w1.y;
            int t2 = ((k + 84) * m) % N;
            float2 w2 = wtab[t2];
            ws[OFF_M2T + 2 * id] = w2.x * inv;  ws[OFF_M2T + 2 * id + 1] = w2.y * inv;
        } else {
            // M3T84: id = m*CROP + kk, m<84, kk<120
            int id = (bx - 218) * 256 + t;
            if (id >= HCOL * CROP) return;
            int m = id / CROP, kk = id % CROP;
            int t3 = ((kk + 108) * ((m + 83) % N)) % N;
            float2 w3 = wtab[t3];
            ws[OFF_M3T84 + 2 * id] = w3.x * inv;
            ws[OFF_M3T84 + 2 * id + 1] = w3.y * inv;
        }
    } else if (bx < 699) {
        int id = (bx - 258) * 256 + t;
        if (id >= 16 * MP * MP) return;
        int rc = id % (MP * MP);
        int r = rc / MP, c = rc % MP;
        float y = r - 41.5f, x = c - 41.5f;
        float2 v = {0.f, 0.f};
        if (x * x + y * y <= 1764.0f) {
            float sp, cp; sincosf(P[id], &sp, &cp);
            v.x = cp; v.y = sp;
        }
        ((float2*)(ws + OFF_PC))[id] = v;
    } else {
        __shared__ int red[256];
        int cnt = 0;
        for (int i = t; i < MP * MP; i += 256) {
            int r = i / MP, c = i % MP;
            float y = r - 41.5f, x = c - 41.5f;
            if (x * x + y * y <= 1764.0f) cnt++;
        }
        red[t] = cnt; __syncthreads();
        for (int s = 128; s > 0; s >>= 1) { if (t < s) red[t] += red[t + s]; __syncthreads(); }
        if (t == 0) ws[OFF_AMP] = (float)red[0];
    }
}

// ---------------- fused stage 1: T1 rows (LDS) -> X rows, per (row-pair, b) ----------------
__global__ __launch_bounds__(192) void k_rcx(const float* __restrict__ x, float* ws) {
    int kp = blockIdx.x, bj = blockIdx.y, tid = threadIdx.x;
    int k0 = kp * 2;
    __shared__ float2 m1w[2][NP];
    __shared__ __align__(16) float2 t1s[2][NP];   // row stride 720B (16B mult)
    const float2* M1 = (const float2*)(ws + OFF_M1);
    for (int idx = tid; idx < 2 * NP; idx += 192) {
        int r = idx / NP, m = idx % NP;
        if (k0 + r < N) m1w[r][m] = M1[(k0 + r) * N + 39 + m];
    }
    __syncthreads();
    {   // T1 rows (same loop/order as old k_rows z=0)
        int grp = tid / 96, tcol = tid % 96;
        if (tcol < NP && k0 + grp < N) {
            float2 acc = {0.f, 0.f};
            for (int nr = 0; nr < NP; nr++) {
                float2 w = m1w[grp][nr];
                float xv = x[(bj * NP + nr) * NP + tcol];
                acc.x += w.x * xv; acc.y += w.y * xv;
            }
            t1s[grp][tcol] = acc;
        }
    }
    __syncthreads();
    // X rows (same pairing/order as old k_cols X-part)
    int col = tid % HCOL, grp = tid / HCOL;
    if (grp >= 2) return;
    int kr = k0 + grp;
    if (kr >= N) return;
    const float2* M1T = (const float2*)(ws + OFF_M1T);
    float2 acc = {0.f, 0.f};
#pragma unroll 5
    for (int ncp = 0; ncp < 45; ncp++) {
        int nc = 2 * ncp;
        float4 u = *(const float4*)&t1s[grp][nc];
        float2 w0 = M1T[(39 + nc) * N + col];
        float2 w1 = M1T[(40 + nc) * N + col];
        acc.x += u.x * w0.x - u.y * w0.y;
        acc.y += u.x * w0.y + u.y * w0.x;
        acc.x += u.z * w1.x - u.w * w1.y;
        acc.y += u.z * w1.y + u.w * w1.x;
    }
    ((float2*)(ws + OFF_X))[((size_t)bj * N + kr) * HCOL + col] = acc;
}

// ---------------- fused stage 2: T2 rows (c, c+8) -> A rows -> Bd row -> T3 row ----------------
__global__ __launch_bounds__(192) void k_rca(float* ws) {
    int kp = blockIdx.x, c = blockIdx.y, tid = threadIdx.x;
    int k0 = kp * 2;
    __shared__ float2 wfw[2][MP];
    __shared__ __align__(16) float2 t2s[2][2][MP];   // [jhalf][row][col], stride 672B
    __shared__ float bds[2][N];
    const float2* WF = (const float2*)(ws + OFF_WF);
    for (int idx = tid; idx < 2 * MP; idx += 192) {
        int r = idx / MP, m = idx % MP;
        if (k0 + r < N) wfw[r][m] = WF[(k0 + r) * N + 42 + m];
    }
    __syncthreads();
    // T2 rows for j = c and j = c+8 (same loop/order as old k_rows z=1)
#pragma unroll
    for (int pass = 0; pass < 2; pass++) {
        int jj = (pass == 0) ? c : c + 8;
        int grp = tid / 96, tcol = tid % 96;
        if (tcol < MP && k0 + grp < N) {
            const float2* PC = (const float2*)(ws + OFF_PC) + (size_t)jj * MP * MP;
            float2 acc = {0.f, 0.f};
            for (int nr = 0; nr < MP; nr++) {
                float2 w = wfw[grp][nr];
                float2 pc = PC[nr * MP + tcol];
                acc.x += w.x * pc.x - w.y * pc.y;
                acc.y += w.x * pc.y + w.y * pc.x;
            }
            t2s[pass][grp][tcol] = acc;
        }
    }
    __syncthreads();
    // A rows (both halves) + Bd rows (same pairing/order as old k_cols A-part + k_bd)
    if (tid < N) {
        float inv_amp = 1.0f / ws[OFF_AMP];
#pragma unroll
        for (int rr = 0; rr < 2; rr++) {
            if (k0 + rr < N) {
                float2 a0 = {0.f, 0.f}, a1 = {0.f, 0.f};
                for (int ncp = 0; ncp < 42; ncp++) {
                    int nc = 2 * ncp;
                    float2 w0 = WF[(42 + nc) * N + tid];
                    float2 w1 = WF[(43 + nc) * N + tid];
                    float4 u0 = *(const float4*)&t2s[0][rr][nc];
                    a0.x += u0.x * w0.x - u0.y * w0.y;
                    a0.y += u0.x * w0.y + u0.y * w0.x;
                    a0.x += u0.z * w1.x - u0.w * w1.y;
                    a0.y += u0.z * w1.y + u0.w * w1.x;
                    float4 u1 = *(const float4*)&t2s[1][rr][nc];
                    a1.x += u1.x * w0.x - u1.y * w0.y;
                    a1.y += u1.x * w0.y + u1.y * w0.x;
                    a1.x += u1.z * w1.x - u1.w * w1.y;
                    a1.y += u1.z * w1.y + u1.w * w1.x;
                }
                bds[rr][tid] = (a0.x * a0.x + a0.y * a0.y - a1.x * a1.x - a1.y * a1.y) * inv_amp;
            }
        }
    }
    __syncthreads();
    // T3 rows (same loop/order as old k2c)
    {
        int grp = tid / 96, col = tid % 96;
        if (col < HCOL && k0 + grp < N) {
            const float2* M2T = (const float2*)(ws + OFF_M2T);
            float2 acc = {0.f, 0.f};
            for (int m = 0; m < N; m++) {
                float bv = bds[grp][m];
                float2 w = M2T[m * N + col];
                acc.x += w.x * bv; acc.y += w.y * bv;
            }
            ((float2*)(ws + OFF_T3))[((size_t)c * N + k0 + grp) * HCOL + col] = acc;
        }
    }
}

// ---------------- stage 2d: OTF[i, 0..83] = sum_k M2[i,k] * T3[k,t] ----------------
__global__ __launch_bounds__(192) void k2d(float* ws) {
    int chunk = blockIdx.x, c = blockIdx.y, tid = threadIdx.x;
    int i0 = chunk * 2;
    __shared__ float2 m2s[2][N];
    // M2[i][k] = conj-free: recompute from M2T (M2[i][k] == M2T[k][i] values are
    // the same table: M2[i][k] uses t2 = ((i+84)*k)%N). Read M2T transposed rows:
    // M2T[k*N + i] over k is a strided read; instead stage from M2T columns via
    // coalesced loop (k runs over idx, i fixed per row) — same values as before.
    const float2* M2T = (const float2*)(ws + OFF_M2T);
    for (int idx = tid; idx < 2 * N; idx += 192) {
        int r = idx / N, k = idx % N;
        if (i0 + r < N) m2s[r][k] = M2T[k * N + (i0 + r)];
    }
    __syncthreads();
    int col = tid % HCOL, grp = tid / HCOL;
    if (grp >= 2) return;
    int i = i0 + grp;
    if (i >= N) return;
    const float2* T3 = (const float2*)(ws + OFF_T3) + (size_t)c * N * HCOL;
    float2 acc = {0.f, 0.f};
    for (int k = 0; k < N; k++) {
        float2 w = m2s[grp][k];
        float2 u = T3[k * HCOL + col];
        acc.x += u.x * w.x - u.y * w.y;
        acc.y += u.x * w.y + u.y * w.x;
    }
    ((float2*)(ws + OFF_OTF))[((size_t)c * N + i) * HCOL + col] = acc;
}

// ---------------- stage 3 fused: 12 rows/block, dbuf, KCH=12 (VGPR<=64) ----------------
constexpr int K34R = 12;
constexpr int KCH  = 12;
constexpr int NT34 = (N + KCH - 1) / KCH;   // 14 (13 full + tail 11)

constexpr int SM_ZS   = 0;
constexpr int SM_M3C  = SM_ZS + 2 * KCH * HCOL * 2;      // 4032
constexpr int SM_PHIS = SM_M3C + 2 * KCH * K34R * 2;     // 4608
constexpr int SM_PM   = SM_PHIS + N * 2;                 // 4942
constexpr int SM_TOT  = SM_PM + 4 * CROP;                // 5422 floats = 21688 B

constexpr int ZBUF = KCH * HCOL;
constexpr int MBUF = KCH * K34R;

#define K34_FMA_BODY(kl)                                                        \
    {                                                                           \
        float4 zz = *(const float4*)&zcur[(kl) * HCOL + 2 * pair];              \
        float4 wa = *(const float4*)&mcur[(kl) * K34R + r0];                    \
        a00.x += wa.x * zz.x - wa.y * zz.y;  a00.y += wa.x * zz.y + wa.y * zz.x;\
        a01.x += wa.x * zz.z - wa.y * zz.w;  a01.y += wa.x * zz.w + wa.y * zz.z;\
        a10.x += wa.z * zz.x - wa.w * zz.y;  a10.y += wa.z * zz.y + wa.w * zz.x;\
        a11.x += wa.z * zz.z - wa.w * zz.w;  a11.y += wa.z * zz.w + wa.w * zz.z;\
    }

__global__ __launch_bounds__(256) void k34(float* ws) {
    int chunk = blockIdx.x, c = blockIdx.y, b = blockIdx.z, tid = threadIdx.x;
    int i0 = chunk * K34R;
    __shared__ __align__(16) float smem[SM_TOT];
    float2* zbase = (float2*)(smem + SM_ZS);
    float2* mbase = (float2*)(smem + SM_M3C);
    float2* phis  = (float2*)(smem + SM_PHIS);
    float*  pmf   = smem + SM_PM;
    float2 (*us)[HCOL] = (float2 (*)[HCOL])(smem + SM_ZS);   // alias: zs dead after loop

    const float2* M3 = (const float2*)(ws + OFF_M3);
    const float4* X4   = (const float4*)(ws + OFF_X   + (size_t)b * N * HCOL * 2);
    const float4* OTF4 = (const float4*)(ws + OFF_OTF + (size_t)c * N * HCOL * 2);
    for (int idx = tid; idx < N; idx += 256) phis[idx] = ((const float2*)(ws + OFF_PHI2))[idx];

    int qkl[2], qcp[2];
#pragma unroll
    for (int e = 0; e < 2; e++) {
        int idx = tid + e * 256;
        qkl[e] = idx / 42; qcp[e] = idx - qkl[e] * 42;
    }
    int mkl = tid % 12, mr = tid / 12;   // tid<144: m3c coords

    int pair = tid % 42, grp = tid / 42;
    int r0 = grp * 2;
    float2 a00 = {0.f,0.f}, a01 = {0.f,0.f}, a10 = {0.f,0.f}, a11 = {0.f,0.f};

    float4 xq[2], oq[2];
    float2 m3r;

#pragma unroll
    for (int e = 0; e < 2; e++)
        if (qkl[e] < KCH) { xq[e] = X4[qkl[e] * 42 + qcp[e]]; oq[e] = OTF4[qkl[e] * 42 + qcp[e]]; }
    if (tid < 144) m3r = M3[(i0 + mr) * N + mkl];
#pragma unroll
    for (int e = 0; e < 2; e++)
        if (qkl[e] < KCH) {
            float4 z;
            z.x = xq[e].x * oq[e].x - xq[e].y * oq[e].y;
            z.y = xq[e].x * oq[e].y + xq[e].y * oq[e].x;
            z.z = xq[e].z * oq[e].z - xq[e].w * oq[e].w;
            z.w = xq[e].z * oq[e].w + xq[e].w * oq[e].z;
            *(float4*)&zbase[qkl[e] * HCOL + 2 * qcp[e]] = z;
        }
    if (tid < 144) mbase[mkl * K34R + mr] = m3r;
    __syncthreads();

    for (int t = 0; t < NT34; t++) {
        int cbuf = t & 1, nbuf = cbuf ^ 1;
        int kr0 = t * KCH;
        int chn = min(KCH, N - kr0);
        int nbase = kr0 + KCH;
        int nchn = (t + 1 < NT34) ? (N - nbase < KCH ? N - nbase : KCH) : 0;
        if (nchn > 0) {
#pragma unroll
            for (int e = 0; e < 2; e++)
                if (qkl[e] < nchn) { xq[e] = X4[(nbase + qkl[e]) * 42 + qcp[e]];
                                     oq[e] = OTF4[(nbase + qkl[e]) * 42 + qcp[e]]; }
            if (tid < 144 && mkl < nchn) m3r = M3[(i0 + mr) * N + nbase + mkl];
        }
        const float2* zcur = zbase + cbuf * ZBUF;
        const float2* mcur = mbase + cbuf * MBUF;
        if (grp < 6) {
            if (chn == KCH) {
#pragma unroll
                for (int kl = 0; kl < KCH; kl++) K34_FMA_BODY(kl)
            } else {
#pragma unroll
                for (int kl = 0; kl < KCH - 1; kl++) K34_FMA_BODY(kl)   // tail chn = 11
            }
        }
        if (nchn > 0) {
            float2* znxt = zbase + nbuf * ZBUF;
            float2* mnxt = mbase + nbuf * MBUF;
#pragma unroll
            for (int e = 0; e < 2; e++)
                if (qkl[e] < nchn) {
                    float4 z;
                    z.x = xq[e].x * oq[e].x - xq[e].y * oq[e].y;
                    z.y = xq[e].x * oq[e].y + xq[e].y * oq[e].x;
                    z.z = xq[e].z * oq[e].z - xq[e].w * oq[e].w;
                    z.w = xq[e].z * oq[e].w + xq[e].w * oq[e].z;
                    *(float4*)&znxt[qkl[e] * HCOL + 2 * qcp[e]] = z;
                }
            if (tid < 144 && mkl < nchn) mnxt[mkl * K34R + mr] = m3r;
        }
        __syncthreads();
    }

    if (grp < 6) {
        *(float4*)&us[r0][2 * pair]     = make_float4(a00.x, a00.y, a01.x, a01.y);
        *(float4*)&us[r0 + 1][2 * pair] = make_float4(a10.x, a10.y, a11.x, a11.y);
    }
    __syncthreads();

    if (tid < 240) {
        int grp2 = tid / CROP, j = tid % CROP;
        int rbase = grp2 * 6;
        const float2* M3T84 = (const float2*)(ws + OFF_M3T84);
        float2 A[6]; float Bq[6];
#pragma unroll
        for (int q = 0; q < 6; q++) A[q] = make_float2(0.f, 0.f);
#pragma unroll 4
        for (int ncp = 0; ncp < 41; ncp++) {
            int nc = 2 * ncp;
            float2 w0 = M3T84[nc * CROP + j];
            float2 w1 = M3T84[(nc + 1) * CROP + j];
#pragma unroll
            for (int q = 0; q < 6; q++) {
                float4 u = *(const float4*)&us[rbase + q][nc];
                A[q].x += u.x * w0.x - u.y * w0.y;
                A[q].y += u.x * w0.y + u.y * w0.x;
                A[q].x += u.z * w1.x - u.w * w1.y;
                A[q].y += u.z * w1.y + u.w * w1.x;
            }
        }
        {
            float2 w = M3T84[82 * CROP + j];
#pragma unroll
            for (int q = 0; q < 6; q++) {
                float2 u = us[rbase + q][82];
                A[q].x += u.x * w.x - u.y * w.y;
                A[q].y += u.x * w.y + u.y * w.x;
            }
        }
        {
            float2 w = M3T84[(HCOL - 1) * CROP + j];
#pragma unroll
            for (int q = 0; q < 6; q++) {
                float2 u = us[rbase + q][HCOL - 1];
                Bq[q] = u.x * w.x - u.y * w.y;
            }
        }
#pragma unroll
        for (int g = 0; g < 2; g++) {
            float vmax = 0.f;
#pragma unroll
            for (int r = 0; r < 3; r++) {
                int q = g * 3 + r, i = i0 + rbase + q;
                int s = i + j + 49; if (s >= N) s -= N;
                float2 ph = phis[s];
                float val = A[q].x * (1.0f + ph.x) - A[q].y * ph.y + Bq[q];
                unsigned idx = (((unsigned)b * N + (24 + i)) * N + (24 + j)) * 8u + c;
                val += 0.003f * noise_at(idx);
                vmax = fmaxf(vmax, val);
            }
            pmf[(grp2 * 2 + g) * CROP + j] = vmax;
        }
    }
    __syncthreads();
    if (tid < 160) {
        int pr = tid / 40, pc = tid % 40;
        float m = fmaxf(fmaxf(pmf[pr * CROP + 3 * pc], pmf[pr * CROP + 3 * pc + 1]),
                        pmf[pr * CROP + 3 * pc + 2]);
        int prow = chunk * 4 + pr;
        ws[OFF_FLAT + (size_t)b * 12800 + ((size_t)prow * 40 + pc) * 8 + c] = m;
    }
}

// ---------------- stage 4: dense(12800->10) + softmax ----------------
__global__ void k5(const float* __restrict__ W3, const float* __restrict__ b3,
                   const float* __restrict__ ws, float* __restrict__ out) {
    int b = blockIdx.x, t = threadIdx.x;
    __shared__ float red[256][10];
    float acc[10];
#pragma unroll
    for (int o = 0; o < 10; o++) acc[o] = 0.f;
    const float* fl = ws + OFF_FLAT + (size_t)b * 12800;
    for (int f = t; f < 12800; f += 256) {
        float v = fl[f];
#pragma unroll
        for (int o = 0; o < 10; o++) acc[o] = fmaf(v, W3[f * 10 + o], acc[o]);
    }
#pragma unroll
    for (int o = 0; o < 10; o++) red[t][o] = acc[o];
    __syncthreads();
    for (int s = 128; s > 0; s >>= 1) {
        if (t < s) {
#pragma unroll
            for (int o = 0; o < 10; o++) red[t][o] += red[t + s][o];
        }
        __syncthreads();
    }
    if (t == 0) {
        float lg[10], mx = -1e30f;
#pragma unroll
        for (int o = 0; o < 10; o++) { lg[o] = red[0][o] + b3[o]; mx = fmaxf(mx, lg[o]); }
        float sum = 0.f;
#pragma unroll
        for (int o = 0; o < 10; o++) { lg[o] = expf(lg[o] - mx); sum += lg[o]; }
#pragma unroll
        for (int o = 0; o < 10; o++) out[b * 10 + o] = lg[o] / sum;
    }
}

extern "C" void kernel_launch(void* const* d_in, const int* in_sizes, int n_in,
                              void* d_out, int out_size, void* d_ws, size_t ws_size,
                              hipStream_t stream) {
    const float* x  = (const float*)d_in[0];   // [16,90,90,1]
    const float* P  = (const float*)d_in[1];   // [16,84,84]
    const float* W3 = (const float*)d_in[2];   // [12800,10]
    const float* b3 = (const float*)d_in[3];   // [10]
    float* ws  = (float*)d_ws;
    float* out = (float*)d_out;                // [16,10]

    k_prep<<<700, 256, 0, stream>>>(P, ws);
    k_rcx<<<dim3(84, 16), 192, 0, stream>>>(x, ws);
    k_rca<<<dim3(84, 8), 192, 0, stream>>>(ws);
    k2d<<<dim3(84, 8), 192, 0, stream>>>(ws);
    k34<<<dim3(CROP / K34R, 8, 16), 256, 0, stream>>>(ws);
    k5<<<16, 256, 0, stream>>>(W3, b3, ws, out);
}

// Round 18
// 192.555 us; speedup vs baseline: 1.0701x; 1.0362x over previous
//
#include <hip/hip_runtime.h>
#include <math.h>

// ---------------- geometry ----------------
constexpr int N  = 167;          // field grid
constexpr int NN = 167 * 167;    // 27889
constexpr int NP = 90;           // input image
constexpr int MP = 84;           // pupil
constexpr int CROP = 120;
constexpr int HCOL = 84;         // Hermitian-reduced column count (t = 0..83)
constexpr int HALF_SZ = 1784896; // (16*167*167*8)/2  for threefry pairing

// ---------------- ws arena (float offsets) ----------------
constexpr size_t SZ_MAT   = (size_t)NN * 2;
constexpr size_t OFF_M1   = 0;
constexpr size_t OFF_M1T  = OFF_M1 + SZ_MAT;
constexpr size_t OFF_WF   = OFF_M1T + SZ_MAT;
constexpr size_t OFF_M2   = OFF_WF + SZ_MAT;                   // [167][167] c row-major (i,k)
constexpr size_t OFF_M2T  = OFF_M2 + SZ_MAT;
constexpr size_t OFF_M3   = OFF_M2T + SZ_MAT;                  // [120][167] c
constexpr size_t OFF_M3T84= OFF_M3 + (size_t)CROP * N * 2;     // [84][120] c
constexpr size_t OFF_PHI2 = OFF_M3T84 + (size_t)HCOL * CROP * 2; // [167] c
constexpr size_t OFF_AMP  = OFF_PHI2 + (size_t)N * 2;
constexpr size_t OFF_X    = OFF_AMP + 4;                       // [16][167][84] c (16B-aligned)
constexpr size_t OFF_T1   = OFF_X  + (size_t)16 * N * HCOL * 2;// (unused)
constexpr size_t OFF_A    = OFF_T1 + (size_t)16 * N * NP * 2;  // (unused)
constexpr size_t OFF_T2   = OFF_A  + (size_t)16 * NN * 2;      // (unused)
constexpr size_t OFF_BD   = OFF_T2 + (size_t)16 * N * MP * 2;  // (unused)
constexpr size_t OFF_T3   = OFF_BD + (size_t)8 * NN;           // [8][167][84] c
constexpr size_t OFF_OTF  = OFF_T3 + (size_t)8 * N * HCOL * 2; // [8][167][84] c
constexpr size_t OFF_FLAT = OFF_OTF+ (size_t)8 * N * HCOL * 2; // [16][12800]
constexpr size_t OFF_PC   = OFF_FLAT + (size_t)16 * 12800;     // [16][84][84] c
constexpr size_t WS_FLOATS = OFF_PC + (size_t)16 * MP * MP * 2;

// ---------------- helpers ----------------
__device__ __forceinline__ unsigned rotl32(unsigned x, int r) {
    return (x << r) | (x >> (32 - r));
}

// jax.random.normal(key(42), [16,167,167,8]) element at flat index idx
__device__ float noise_at(unsigned idx) {
    unsigned c0, c1; int lane;
    if (idx < (unsigned)HALF_SZ) { c0 = idx; c1 = idx + HALF_SZ; lane = 0; }
    else                         { c0 = idx - HALF_SZ; c1 = idx; lane = 1; }
    const unsigned ks0 = 0u, ks1 = 42u, ks2 = 0x1BD11BDAu ^ 42u;
    unsigned x0 = c0 + ks0, x1 = c1 + ks1;
#define TFR(r) { x0 += x1; x1 = rotl32(x1, r); x1 ^= x0; }
    TFR(13) TFR(15) TFR(26) TFR(6)   x0 += ks1; x1 += ks2 + 1u;
    TFR(17) TFR(29) TFR(16) TFR(24)  x0 += ks2; x1 += ks0 + 2u;
    TFR(13) TFR(15) TFR(26) TFR(6)   x0 += ks0; x1 += ks1 + 3u;
    TFR(17) TFR(29) TFR(16) TFR(24)  x0 += ks1; x1 += ks2 + 4u;
    TFR(13) TFR(15) TFR(26) TFR(6)   x0 += ks2; x1 += ks0 + 5u;
#undef TFR
    unsigned bits = lane ? x1 : x0;
    float u01 = __uint_as_float((bits >> 9) | 0x3F800000u) - 1.0f;
    const float lo = -0.99999994f;
    float f = fmaxf(lo, u01 * 2.0f + lo);
    float w = -log1pf(-f * f);
    float p;
    if (w < 5.0f) {
        w -= 2.5f;
        p = 2.81022636e-08f;
        p = fmaf(p, w, 3.43273939e-07f);
        p = fmaf(p, w, -3.5233877e-06f);
        p = fmaf(p, w, -4.39150654e-06f);
        p = fmaf(p, w, 0.00021858087f);
        p = fmaf(p, w, -0.00125372503f);
        p = fmaf(p, w, -0.00417768164f);
        p = fmaf(p, w, 0.246640727f);
        p = fmaf(p, w, 1.50140941f);
    } else {
        w = sqrtf(w) - 3.0f;
        p = -0.000200214257f;
        p = fmaf(p, w, 0.000100950558f);
        p = fmaf(p, w, 0.00134934322f);
        p = fmaf(p, w, -0.00367342844f);
        p = fmaf(p, w, 0.00573950773f);
        p = fmaf(p, w, -0.0076224613f);
        p = fmaf(p, w, 0.00943887047f);
        p = fmaf(p, w, 1.00167406f);
        p = fmaf(p, w, 2.83297682f);
    }
    return 1.41421356237f * p * f;
}

// ---------------- prep: DFT matrices (all layouts COALESCED) + pupil + amp ----------------
__global__ void k_prep(const float* __restrict__ P, float* ws) {
    int bx = blockIdx.x, t = threadIdx.x;
    if (bx < 258) {
        __shared__ float2 wtab[N];   // wtab[s] = exp(+2pi i s/167)
        const float TPI = (float)(6.283185307179586476925286766559 / 167.0);
        for (int i = t; i < N; i += 256) {
            float s, c; sincosf(TPI * (float)i, &s, &c);
            wtab[i] = make_float2(c, s);
        }
        __syncthreads();
        const float inv = 1.0f / 167.0f;
        if (bx < 109) {
            // row-major layouts: id = k*N + m
            int id = bx * 256 + t;
            if (id >= NN) return;
            int k = id / N, m = id % N;
            int t1 = ((k + 84) * ((m + 83) % N)) % N;
            float2 w1 = wtab[t1];
            ws[OFF_M1 + 2 * id] = w1.x;  ws[OFF_M1 + 2 * id + 1] = -w1.y;
            int tw = (k * m) % N;
            float2 ww = wtab[tw];
            ws[OFF_WF + 2 * id] = ww.x;  ws[OFF_WF + 2 * id + 1] = -ww.y;
            int t2 = ((k + 84) * m) % N;   // M2[i=k][k=m]
            float2 w2 = wtab[t2];
            ws[OFF_M2 + 2 * id] = w2.x * inv;  ws[OFF_M2 + 2 * id + 1] = w2.y * inv;
            if (k < CROP) {
                int t3 = ((k + 108) * ((m + 83) % N)) % N;
                float2 w3 = wtab[t3];
                ws[OFF_M3 + 2 * (k * N + m)] = w3.x * inv;
                ws[OFF_M3 + 2 * (k * N + m) + 1] = w3.y * inv;
            }
            if (id < N) {
                float2 wp = wtab[(2 * id) % N];
                ws[OFF_PHI2 + 2 * id] = wp.x;
                ws[OFF_PHI2 + 2 * id + 1] = wp.y;
            }
        } else if (bx < 218) {
            // transposed layouts: id = m*N + k  (coalesced store)
            int id = (bx - 109) * 256 + t;
            if (id >= NN) return;
            int m = id / N, k = id % N;
            int t1 = ((k + 84) * ((m + 83) % N)) % N;
            float2 w1 = wtab[t1];
            ws[OFF_M1T + 2 * id] = w1.x;  ws[OFF_M1T + 2 * id + 1] = -w1.y;
            int t2 = ((k + 84) * m) % N;
            float2 w2 = wtab[t2];
            ws[OFF_M2T + 2 * id] = w2.x * inv;  ws[OFF_M2T + 2 * id + 1] = w2.y * inv;
        } else {
            // M3T84: id = m*CROP + kk, m<84, kk<120
            int id = (bx - 218) * 256 + t;
            if (id >= HCOL * CROP) return;
            int m = id / CROP, kk = id % CROP;
            int t3 = ((kk + 108) * ((m + 83) % N)) % N;
            float2 w3 = wtab[t3];
            ws[OFF_M3T84 + 2 * id] = w3.x * inv;
            ws[OFF_M3T84 + 2 * id + 1] = w3.y * inv;
        }
    } else if (bx < 699) {
        int id = (bx - 258) * 256 + t;
        if (id >= 16 * MP * MP) return;
        int rc = id % (MP * MP);
        int r = rc / MP, c = rc % MP;
        float y = r - 41.5f, x = c - 41.5f;
        float2 v = {0.f, 0.f};
        if (x * x + y * y <= 1764.0f) {
            float sp, cp; sincosf(P[id], &sp, &cp);
            v.x = cp; v.y = sp;
        }
        ((float2*)(ws + OFF_PC))[id] = v;
    } else {
        __shared__ int red[256];
        int cnt = 0;
        for (int i = t; i < MP * MP; i += 256) {
            int r = i / MP, c = i % MP;
            float y = r - 41.5f, x = c - 41.5f;
            if (x * x + y * y <= 1764.0f) cnt++;
        }
        red[t] = cnt; __syncthreads();
        for (int s = 128; s > 0; s >>= 1) { if (t < s) red[t] += red[t + s]; __syncthreads(); }
        if (t == 0) ws[OFF_AMP] = (float)red[0];
    }
}

// ---------------- fused stage 1 (both paths, blockIdx.z dispatch) ----------------
// z=0: T1 rows (LDS) -> X rows, per (row-pair, b=0..15)
// z=1: T2 rows (c, c+8) -> A rows -> Bd row -> T3 row, per (row-pair, c=0..7)
__global__ __launch_bounds__(192) void k_s1(const float* __restrict__ x, float* ws) {
    int kp = blockIdx.x, tid = threadIdx.x;
    int k0 = kp * 2;
    if (blockIdx.z == 0) {
        int bj = blockIdx.y;
        __shared__ float2 m1w[2][NP];
        __shared__ __align__(16) float2 t1s[2][NP];
        const float2* M1 = (const float2*)(ws + OFF_M1);
        for (int idx = tid; idx < 2 * NP; idx += 192) {
            int r = idx / NP, m = idx % NP;
            if (k0 + r < N) m1w[r][m] = M1[(k0 + r) * N + 39 + m];
        }
        __syncthreads();
        {   // T1 rows
            int grp = tid / 96, tcol = tid % 96;
            if (tcol < NP && k0 + grp < N) {
                float2 acc = {0.f, 0.f};
                for (int nr = 0; nr < NP; nr++) {
                    float2 w = m1w[grp][nr];
                    float xv = x[(bj * NP + nr) * NP + tcol];
                    acc.x += w.x * xv; acc.y += w.y * xv;
                }
                t1s[grp][tcol] = acc;
            }
        }
        __syncthreads();
        // X rows
        int col = tid % HCOL, grp = tid / HCOL;
        if (grp >= 2) return;
        int kr = k0 + grp;
        if (kr >= N) return;
        const float2* M1T = (const float2*)(ws + OFF_M1T);
        float2 acc = {0.f, 0.f};
#pragma unroll 5
        for (int ncp = 0; ncp < 45; ncp++) {
            int nc = 2 * ncp;
            float4 u = *(const float4*)&t1s[grp][nc];
            float2 w0 = M1T[(39 + nc) * N + col];
            float2 w1 = M1T[(40 + nc) * N + col];
            acc.x += u.x * w0.x - u.y * w0.y;
            acc.y += u.x * w0.y + u.y * w0.x;
            acc.x += u.z * w1.x - u.w * w1.y;
            acc.y += u.z * w1.y + u.w * w1.x;
        }
        ((float2*)(ws + OFF_X))[((size_t)bj * N + kr) * HCOL + col] = acc;
    } else {
        int c = blockIdx.y;
        if (c >= 8) return;
        __shared__ float2 wfw[2][MP];
        __shared__ __align__(16) float2 t2s[2][2][MP];
        __shared__ float bds[2][N];
        const float2* WF = (const float2*)(ws + OFF_WF);
        for (int idx = tid; idx < 2 * MP; idx += 192) {
            int r = idx / MP, m = idx % MP;
            if (k0 + r < N) wfw[r][m] = WF[(k0 + r) * N + 42 + m];
        }
        __syncthreads();
#pragma unroll
        for (int pass = 0; pass < 2; pass++) {
            int jj = (pass == 0) ? c : c + 8;
            int grp = tid / 96, tcol = tid % 96;
            if (tcol < MP && k0 + grp < N) {
                const float2* PC = (const float2*)(ws + OFF_PC) + (size_t)jj * MP * MP;
                float2 acc = {0.f, 0.f};
                for (int nr = 0; nr < MP; nr++) {
                    float2 w = wfw[grp][nr];
                    float2 pc = PC[nr * MP + tcol];
                    acc.x += w.x * pc.x - w.y * pc.y;
                    acc.y += w.x * pc.y + w.y * pc.x;
                }
                t2s[pass][grp][tcol] = acc;
            }
        }
        __syncthreads();
        if (tid < N) {
            float inv_amp = 1.0f / ws[OFF_AMP];
#pragma unroll
            for (int rr = 0; rr < 2; rr++) {
                if (k0 + rr < N) {
                    float2 a0 = {0.f, 0.f}, a1 = {0.f, 0.f};
                    for (int ncp = 0; ncp < 42; ncp++) {
                        int nc = 2 * ncp;
                        float2 w0 = WF[(42 + nc) * N + tid];
                        float2 w1 = WF[(43 + nc) * N + tid];
                        float4 u0 = *(const float4*)&t2s[0][rr][nc];
                        a0.x += u0.x * w0.x - u0.y * w0.y;
                        a0.y += u0.x * w0.y + u0.y * w0.x;
                        a0.x += u0.z * w1.x - u0.w * w1.y;
                        a0.y += u0.z * w1.y + u0.w * w1.x;
                        float4 u1 = *(const float4*)&t2s[1][rr][nc];
                        a1.x += u1.x * w0.x - u1.y * w0.y;
                        a1.y += u1.x * w0.y + u1.y * w0.x;
                        a1.x += u1.z * w1.x - u1.w * w1.y;
                        a1.y += u1.z * w1.y + u1.w * w1.x;
                    }
                    bds[rr][tid] = (a0.x * a0.x + a0.y * a0.y - a1.x * a1.x - a1.y * a1.y) * inv_amp;
                }
            }
        }
        __syncthreads();
        {
            int grp = tid / 96, col = tid % 96;
            if (col < HCOL && k0 + grp < N) {
                const float2* M2T = (const float2*)(ws + OFF_M2T);
                float2 acc = {0.f, 0.f};
                for (int m = 0; m < N; m++) {
                    float bv = bds[grp][m];
                    float2 w = M2T[m * N + col];
                    acc.x += w.x * bv; acc.y += w.y * bv;
                }
                ((float2*)(ws + OFF_T3))[((size_t)c * N + k0 + grp) * HCOL + col] = acc;
            }
        }
    }
}

// ---------------- stage 2d: OTF[i, 0..83] = sum_k M2[i,k] * T3[k,t] ----------------
__global__ __launch_bounds__(192) void k2d(float* ws) {
    int chunk = blockIdx.x, c = blockIdx.y, tid = threadIdx.x;
    int i0 = chunk * 2;
    __shared__ float2 m2s[2][N];
    const float2* M2 = (const float2*)(ws + OFF_M2);
    for (int idx = tid; idx < 2 * N; idx += 192) {
        int r = idx / N, k = idx % N;
        if (i0 + r < N) m2s[r][k] = M2[(size_t)(i0 + r) * N + k];   // coalesced
    }
    __syncthreads();
    int col = tid % HCOL, grp = tid / HCOL;
    if (grp >= 2) return;
    int i = i0 + grp;
    if (i >= N) return;
    const float2* T3 = (const float2*)(ws + OFF_T3) + (size_t)c * N * HCOL;
    float2 acc = {0.f, 0.f};
    for (int k = 0; k < N; k++) {
        float2 w = m2s[grp][k];
        float2 u = T3[k * HCOL + col];
        acc.x += u.x * w.x - u.y * w.y;
        acc.y += u.x * w.y + u.y * w.x;
    }
    ((float2*)(ws + OFF_OTF))[((size_t)c * N + i) * HCOL + col] = acc;
}

// ---------------- stage 3 fused: 12 rows/block, dbuf, KCH=12 (VGPR<=64) ----------------
constexpr int K34R = 12;
constexpr int KCH  = 12;
constexpr int NT34 = (N + KCH - 1) / KCH;   // 14 (13 full + tail 11)

constexpr int SM_ZS   = 0;
constexpr int SM_M3C  = SM_ZS + 2 * KCH * HCOL * 2;      // 4032
constexpr int SM_PHIS = SM_M3C + 2 * KCH * K34R * 2;     // 4608
constexpr int SM_PM   = SM_PHIS + N * 2;                 // 4942
constexpr int SM_TOT  = SM_PM + 4 * CROP;                // 5422 floats = 21688 B

constexpr int ZBUF = KCH * HCOL;
constexpr int MBUF = KCH * K34R;

#define K34_FMA_BODY(kl)                                                        \
    {                                                                           \
        float4 zz = *(const float4*)&zcur[(kl) * HCOL + 2 * pair];              \
        float4 wa = *(const float4*)&mcur[(kl) * K34R + r0];                    \
        a00.x += wa.x * zz.x - wa.y * zz.y;  a00.y += wa.x * zz.y + wa.y * zz.x;\
        a01.x += wa.x * zz.z - wa.y * zz.w;  a01.y += wa.x * zz.w + wa.y * zz.z;\
        a10.x += wa.z * zz.x - wa.w * zz.y;  a10.y += wa.z * zz.y + wa.w * zz.x;\
        a11.x += wa.z * zz.z - wa.w * zz.w;  a11.y += wa.z * zz.w + wa.w * zz.z;\
    }

__global__ __launch_bounds__(256) void k34(float* ws) {
    int chunk = blockIdx.x, c = blockIdx.y, b = blockIdx.z, tid = threadIdx.x;
    int i0 = chunk * K34R;
    __shared__ __align__(16) float smem[SM_TOT];
    float2* zbase = (float2*)(smem + SM_ZS);
    float2* mbase = (float2*)(smem + SM_M3C);
    float2* phis  = (float2*)(smem + SM_PHIS);
    float*  pmf   = smem + SM_PM;
    float2 (*us)[HCOL] = (float2 (*)[HCOL])(smem + SM_ZS);   // alias: zs dead after loop

    const float2* M3 = (const float2*)(ws + OFF_M3);
    const float4* X4   = (const float4*)(ws + OFF_X   + (size_t)b * N * HCOL * 2);
    const float4* OTF4 = (const float4*)(ws + OFF_OTF + (size_t)c * N * HCOL * 2);
    for (int idx = tid; idx < N; idx += 256) phis[idx] = ((const float2*)(ws + OFF_PHI2))[idx];

    int qkl[2], qcp[2];
#pragma unroll
    for (int e = 0; e < 2; e++) {
        int idx = tid + e * 256;
        qkl[e] = idx / 42; qcp[e] = idx - qkl[e] * 42;
    }
    int mkl = tid % 12, mr = tid / 12;   // tid<144: m3c coords

    int pair = tid % 42, grp = tid / 42;
    int r0 = grp * 2;
    float2 a00 = {0.f,0.f}, a01 = {0.f,0.f}, a10 = {0.f,0.f}, a11 = {0.f,0.f};

    float4 xq[2], oq[2];
    float2 m3r;

#pragma unroll
    for (int e = 0; e < 2; e++)
        if (qkl[e] < KCH) { xq[e] = X4[qkl[e] * 42 + qcp[e]]; oq[e] = OTF4[qkl[e] * 42 + qcp[e]]; }
    if (tid < 144) m3r = M3[(i0 + mr) * N + mkl];
#pragma unroll
    for (int e = 0; e < 2; e++)
        if (qkl[e] < KCH) {
            float4 z;
            z.x = xq[e].x * oq[e].x - xq[e].y * oq[e].y;
            z.y = xq[e].x * oq[e].y + xq[e].y * oq[e].x;
            z.z = xq[e].z * oq[e].z - xq[e].w * oq[e].w;
            z.w = xq[e].z * oq[e].w + xq[e].w * oq[e].z;
            *(float4*)&zbase[qkl[e] * HCOL + 2 * qcp[e]] = z;
        }
    if (tid < 144) mbase[mkl * K34R + mr] = m3r;
    __syncthreads();

    for (int t = 0; t < NT34; t++) {
        int cbuf = t & 1, nbuf = cbuf ^ 1;
        int kr0 = t * KCH;
        int chn = min(KCH, N - kr0);
        int nbase = kr0 + KCH;
        int nchn = (t + 1 < NT34) ? (N - nbase < KCH ? N - nbase : KCH) : 0;
        if (nchn > 0) {
#pragma unroll
            for (int e = 0; e < 2; e++)
                if (qkl[e] < nchn) { xq[e] = X4[(nbase + qkl[e]) * 42 + qcp[e]];
                                     oq[e] = OTF4[(nbase + qkl[e]) * 42 + qcp[e]]; }
            if (tid < 144 && mkl < nchn) m3r = M3[(i0 + mr) * N + nbase + mkl];
        }
        const float2* zcur = zbase + cbuf * ZBUF;
        const float2* mcur = mbase + cbuf * MBUF;
        if (grp < 6) {
            if (chn == KCH) {
#pragma unroll
                for (int kl = 0; kl < KCH; kl++) K34_FMA_BODY(kl)
            } else {
#pragma unroll
                for (int kl = 0; kl < KCH - 1; kl++) K34_FMA_BODY(kl)   // tail chn = 11
            }
        }
        if (nchn > 0) {
            float2* znxt = zbase + nbuf * ZBUF;
            float2* mnxt = mbase + nbuf * MBUF;
#pragma unroll
            for (int e = 0; e < 2; e++)
                if (qkl[e] < nchn) {
                    float4 z;
                    z.x = xq[e].x * oq[e].x - xq[e].y * oq[e].y;
                    z.y = xq[e].x * oq[e].y + xq[e].y * oq[e].x;
                    z.z = xq[e].z * oq[e].z - xq[e].w * oq[e].w;
                    z.w = xq[e].z * oq[e].w + xq[e].w * oq[e].z;
                    *(float4*)&znxt[qkl[e] * HCOL + 2 * qcp[e]] = z;
                }
            if (tid < 144 && mkl < nchn) mnxt[mkl * K34R + mr] = m3r;
        }
        __syncthreads();
    }

    if (grp < 6) {
        *(float4*)&us[r0][2 * pair]     = make_float4(a00.x, a00.y, a01.x, a01.y);
        *(float4*)&us[r0 + 1][2 * pair] = make_float4(a10.x, a10.y, a11.x, a11.y);
    }
    __syncthreads();

    if (tid < 240) {
        int grp2 = tid / CROP, j = tid % CROP;
        int rbase = grp2 * 6;
        const float2* M3T84 = (const float2*)(ws + OFF_M3T84);
        float2 A[6]; float Bq[6];
#pragma unroll
        for (int q = 0; q < 6; q++) A[q] = make_float2(0.f, 0.f);
#pragma unroll 4
        for (int ncp = 0; ncp < 41; ncp++) {
            int nc = 2 * ncp;
            float2 w0 = M3T84[nc * CROP + j];
            float2 w1 = M3T84[(nc + 1) * CROP + j];
#pragma unroll
            for (int q = 0; q < 6; q++) {
                float4 u = *(const float4*)&us[rbase + q][nc];
                A[q].x += u.x * w0.x - u.y * w0.y;
                A[q].y += u.x * w0.y + u.y * w0.x;
                A[q].x += u.z * w1.x - u.w * w1.y;
                A[q].y += u.z * w1.y + u.w * w1.x;
            }
        }
        {
            float2 w = M3T84[82 * CROP + j];
#pragma unroll
            for (int q = 0; q < 6; q++) {
                float2 u = us[rbase + q][82];
                A[q].x += u.x * w.x - u.y * w.y;
                A[q].y += u.x * w.y + u.y * w.x;
            }
        }
        {
            float2 w = M3T84[(HCOL - 1) * CROP + j];
#pragma unroll
            for (int q = 0; q < 6; q++) {
                float2 u = us[rbase + q][HCOL - 1];
                Bq[q] = u.x * w.x - u.y * w.y;
            }
        }
#pragma unroll
        for (int g = 0; g < 2; g++) {
            float vmax = 0.f;
#pragma unroll
            for (int r = 0; r < 3; r++) {
                int q = g * 3 + r, i = i0 + rbase + q;
                int s = i + j + 49; if (s >= N) s -= N;
                float2 ph = phis[s];
                float val = A[q].x * (1.0f + ph.x) - A[q].y * ph.y + Bq[q];
                unsigned idx = (((unsigned)b * N + (24 + i)) * N + (24 + j)) * 8u + c;
                val += 0.003f * noise_at(idx);
                vmax = fmaxf(vmax, val);
            }
            pmf[(grp2 * 2 + g) * CROP + j] = vmax;
        }
    }
    __syncthreads();
    if (tid < 160) {
        int pr = tid / 40, pc = tid % 40;
        float m = fmaxf(fmaxf(pmf[pr * CROP + 3 * pc], pmf[pr * CROP + 3 * pc + 1]),
                        pmf[pr * CROP + 3 * pc + 2]);
        int prow = chunk * 4 + pr;
        ws[OFF_FLAT + (size_t)b * 12800 + ((size_t)prow * 40 + pc) * 8 + c] = m;
    }
}

// ---------------- stage 4: dense(12800->10) + softmax ----------------
__global__ void k5(const float* __restrict__ W3, const float* __restrict__ b3,
                   const float* __restrict__ ws, float* __restrict__ out) {
    int b = blockIdx.x, t = threadIdx.x;
    __shared__ float red[256][10];
    float acc[10];
#pragma unroll
    for (int o = 0; o < 10; o++) acc[o] = 0.f;
    const float* fl = ws + OFF_FLAT + (size_t)b * 12800;
    for (int f = t; f < 12800; f += 256) {
        float v = fl[f];
#pragma unroll
        for (int o = 0; o < 10; o++) acc[o] = fmaf(v, W3[f * 10 + o], acc[o]);
    }
#pragma unroll
    for (int o = 0; o < 10; o++) red[t][o] = acc[o];
    __syncthreads();
    for (int s = 128; s > 0; s >>= 1) {
        if (t < s) {
#pragma unroll
            for (int o = 0; o < 10; o++) red[t][o] += red[t + s][o];
        }
        __syncthreads();
    }
    if (t == 0) {
        float lg[10], mx = -1e30f;
#pragma unroll
        for (int o = 0; o < 10; o++) { lg[o] = red[0][o] + b3[o]; mx = fmaxf(mx, lg[o]); }
        float sum = 0.f;
#pragma unroll
        for (int o = 0; o < 10; o++) { lg[o] = expf(lg[o] - mx); sum += lg[o]; }
#pragma unroll
        for (int o = 0; o < 10; o++) out[b * 10 + o] = lg[o] / sum;
    }
}

extern "C" void kernel_launch(void* const* d_in, const int* in_sizes, int n_in,
                              void* d_out, int out_size, void* d_ws, size_t ws_size,
                              hipStream_t stream) {
    const float* x  = (const float*)d_in[0];   // [16,90,90,1]
    const float* P  = (const float*)d_in[1];   // [16,84,84]
    const float* W3 = (const float*)d_in[2];   // [12800,10]
    const float* b3 = (const float*)d_in[3];   // [10]
    float* ws  = (float*)d_ws;
    float* out = (float*)d_out;                // [16,10]

    k_prep<<<700, 256, 0, stream>>>(P, ws);
    k_s1<<<dim3(84, 16, 2), 192, 0, stream>>>(x, ws);
    k2d<<<dim3(84, 8), 192, 0, stream>>>(ws);
    k34<<<dim3(CROP / K34R, 8, 16), 256, 0, stream>>>(ws);
    k5<<<16, 256, 0, stream>>>(W3, b3, ws, out);
}

// Round 19
// 192.166 us; speedup vs baseline: 1.0722x; 1.0020x over previous
//
#include <hip/hip_runtime.h>
#include <math.h>

// ---------------- geometry ----------------
constexpr int N  = 167;          // field grid
constexpr int NN = 167 * 167;    // 27889
constexpr int NP = 90;           // input image
constexpr int MP = 84;           // pupil
constexpr int CROP = 120;
constexpr int HCOL = 84;         // Hermitian-reduced column count (t = 0..83)
constexpr int HALF_SZ = 1784896; // (16*167*167*8)/2  for threefry pairing

constexpr size_t AL4(size_t v) { return (v + 3) & ~(size_t)3; }   // 16B alignment in floats

// ---------------- ws arena (float offsets, float4-aligned where needed) ----------------
constexpr size_t SZ_MAT   = (size_t)NN * 2;
constexpr size_t OFF_M1   = 0;
constexpr size_t OFF_M1T  = OFF_M1 + SZ_MAT;
constexpr size_t OFF_WF   = OFF_M1T + SZ_MAT;
constexpr size_t OFF_M2   = OFF_WF + SZ_MAT;                   // [167][167] c row-major (i,k)
constexpr size_t OFF_M2T  = OFF_M2 + SZ_MAT;
constexpr size_t OFF_M3   = OFF_M2T + SZ_MAT;                  // [120][167] c
constexpr size_t OFF_M3T84= AL4(OFF_M3 + (size_t)CROP * N * 2);// [84][120] c, 16B-aligned
constexpr size_t OFF_PHI2 = AL4(OFF_M3T84 + (size_t)HCOL * CROP * 2); // [167] c
constexpr size_t OFF_AMP  = OFF_PHI2 + (size_t)N * 2;
constexpr size_t OFF_X    = AL4(OFF_AMP + 4);                  // [16][167][84] c, 16B-aligned
constexpr size_t OFF_T1   = OFF_X  + (size_t)16 * N * HCOL * 2;// (unused)
constexpr size_t OFF_A    = OFF_T1 + (size_t)16 * N * NP * 2;  // (unused)
constexpr size_t OFF_T2   = OFF_A  + (size_t)16 * NN * 2;      // (unused)
constexpr size_t OFF_BD   = OFF_T2 + (size_t)16 * N * MP * 2;  // (unused)
constexpr size_t OFF_T3   = OFF_BD + (size_t)8 * NN;           // [8][167][84] c
constexpr size_t OFF_OTF  = AL4(OFF_T3 + (size_t)8 * N * HCOL * 2); // [8][167][84] c, 16B-aligned
constexpr size_t OFF_FLAT = OFF_OTF+ (size_t)8 * N * HCOL * 2; // [16][12800]
constexpr size_t OFF_PC   = OFF_FLAT + (size_t)16 * 12800;     // [16][84][84] c
constexpr size_t WS_FLOATS = OFF_PC + (size_t)16 * MP * MP * 2;

// ---------------- helpers ----------------
__device__ __forceinline__ unsigned rotl32(unsigned x, int r) {
    return (x << r) | (x >> (32 - r));
}

// jax.random.normal(key(42), [16,167,167,8]) element at flat index idx
__device__ float noise_at(unsigned idx) {
    unsigned c0, c1; int lane;
    if (idx < (unsigned)HALF_SZ) { c0 = idx; c1 = idx + HALF_SZ; lane = 0; }
    else                         { c0 = idx - HALF_SZ; c1 = idx; lane = 1; }
    const unsigned ks0 = 0u, ks1 = 42u, ks2 = 0x1BD11BDAu ^ 42u;
    unsigned x0 = c0 + ks0, x1 = c1 + ks1;
#define TFR(r) { x0 += x1; x1 = rotl32(x1, r); x1 ^= x0; }
    TFR(13) TFR(15) TFR(26) TFR(6)   x0 += ks1; x1 += ks2 + 1u;
    TFR(17) TFR(29) TFR(16) TFR(24)  x0 += ks2; x1 += ks0 + 2u;
    TFR(13) TFR(15) TFR(26) TFR(6)   x0 += ks0; x1 += ks1 + 3u;
    TFR(17) TFR(29) TFR(16) TFR(24)  x0 += ks1; x1 += ks2 + 4u;
    TFR(13) TFR(15) TFR(26) TFR(6)   x0 += ks2; x1 += ks0 + 5u;
#undef TFR
    unsigned bits = lane ? x1 : x0;
    float u01 = __uint_as_float((bits >> 9) | 0x3F800000u) - 1.0f;
    const float lo = -0.99999994f;
    float f = fmaxf(lo, u01 * 2.0f + lo);
    float w = -log1pf(-f * f);
    float p;
    if (w < 5.0f) {
        w -= 2.5f;
        p = 2.81022636e-08f;
        p = fmaf(p, w, 3.43273939e-07f);
        p = fmaf(p, w, -3.5233877e-06f);
        p = fmaf(p, w, -4.39150654e-06f);
        p = fmaf(p, w, 0.00021858087f);
        p = fmaf(p, w, -0.00125372503f);
        p = fmaf(p, w, -0.00417768164f);
        p = fmaf(p, w, 0.246640727f);
        p = fmaf(p, w, 1.50140941f);
    } else {
        w = sqrtf(w) - 3.0f;
        p = -0.000200214257f;
        p = fmaf(p, w, 0.000100950558f);
        p = fmaf(p, w, 0.00134934322f);
        p = fmaf(p, w, -0.00367342844f);
        p = fmaf(p, w, 0.00573950773f);
        p = fmaf(p, w, -0.0076224613f);
        p = fmaf(p, w, 0.00943887047f);
        p = fmaf(p, w, 1.00167406f);
        p = fmaf(p, w, 2.83297682f);
    }
    return 1.41421356237f * p * f;
}

// ---------------- prep: DFT matrices (all layouts COALESCED) + pupil + amp ----------------
__global__ void k_prep(const float* __restrict__ P, float* ws) {
    int bx = blockIdx.x, t = threadIdx.x;
    if (bx < 258) {
        __shared__ float2 wtab[N];   // wtab[s] = exp(+2pi i s/167)
        const float TPI = (float)(6.283185307179586476925286766559 / 167.0);
        for (int i = t; i < N; i += 256) {
            float s, c; sincosf(TPI * (float)i, &s, &c);
            wtab[i] = make_float2(c, s);
        }
        __syncthreads();
        const float inv = 1.0f / 167.0f;
        if (bx < 109) {
            // row-major layouts: id = k*N + m
            int id = bx * 256 + t;
            if (id >= NN) return;
            int k = id / N, m = id % N;
            int t1 = ((k + 84) * ((m + 83) % N)) % N;
            float2 w1 = wtab[t1];
            ws[OFF_M1 + 2 * id] = w1.x;  ws[OFF_M1 + 2 * id + 1] = -w1.y;
            int tw = (k * m) % N;
            float2 ww = wtab[tw];
            ws[OFF_WF + 2 * id] = ww.x;  ws[OFF_WF + 2 * id + 1] = -ww.y;
            int t2 = ((k + 84) * m) % N;   // M2[i=k][k=m]
            float2 w2 = wtab[t2];
            ws[OFF_M2 + 2 * id] = w2.x * inv;  ws[OFF_M2 + 2 * id + 1] = w2.y * inv;
            if (k < CROP) {
                int t3 = ((k + 108) * ((m + 83) % N)) % N;
                float2 w3 = wtab[t3];
                ws[OFF_M3 + 2 * (k * N + m)] = w3.x * inv;
                ws[OFF_M3 + 2 * (k * N + m) + 1] = w3.y * inv;
            }
            if (id < N) {
                float2 wp = wtab[(2 * id) % N];
                ws[OFF_PHI2 + 2 * id] = wp.x;
                ws[OFF_PHI2 + 2 * id + 1] = wp.y;
            }
        } else if (bx < 218) {
            // transposed layouts: id = m*N + k  (coalesced store)
            int id = (bx - 109) * 256 + t;
            if (id >= NN) return;
            int m = id / N, k = id % N;
            int t1 = ((k + 84) * ((m + 83) % N)) % N;
            float2 w1 = wtab[t1];
            ws[OFF_M1T + 2 * id] = w1.x;  ws[OFF_M1T + 2 * id + 1] = -w1.y;
            int t2 = ((k + 84) * m) % N;
            float2 w2 = wtab[t2];
            ws[OFF_M2T + 2 * id] = w2.x * inv;  ws[OFF_M2T + 2 * id + 1] = w2.y * inv;
        } else {
            // M3T84: id = m*CROP + kk, m<84, kk<120
            int id = (bx - 218) * 256 + t;
            if (id >= HCOL * CROP) return;
            int m = id / CROP, kk = id % CROP;
            int t3 = ((kk + 108) * ((m + 83) % N)) % N;
            float2 w3 = wtab[t3];
            ws[OFF_M3T84 + 2 * id] = w3.x * inv;
            ws[OFF_M3T84 + 2 * id + 1] = w3.y * inv;
        }
    } else if (bx < 699) {
        int id = (bx - 258) * 256 + t;
        if (id >= 16 * MP * MP) return;
        int rc = id % (MP * MP);
        int r = rc / MP, c = rc % MP;
        float y = r - 41.5f, x = c - 41.5f;
        float2 v = {0.f, 0.f};
        if (x * x + y * y <= 1764.0f) {
            float sp, cp; sincosf(P[id], &sp, &cp);
            v.x = cp; v.y = sp;
        }
        ((float2*)(ws + OFF_PC))[id] = v;
    } else {
        __shared__ int red[256];
        int cnt = 0;
        for (int i = t; i < MP * MP; i += 256) {
            int r = i / MP, c = i % MP;
            float y = r - 41.5f, x = c - 41.5f;
            if (x * x + y * y <= 1764.0f) cnt++;
        }
        red[t] = cnt; __syncthreads();
        for (int s = 128; s > 0; s >>= 1) { if (t < s) red[t] += red[t + s]; __syncthreads(); }
        if (t == 0) ws[OFF_AMP] = (float)red[0];
    }
}

// ---------------- fused stage 1 (both paths, blockIdx.z dispatch) ----------------
__global__ __launch_bounds__(192) void k_s1(const float* __restrict__ x, float* ws) {
    int kp = blockIdx.x, tid = threadIdx.x;
    int k0 = kp * 2;
    if (blockIdx.z == 0) {
        int bj = blockIdx.y;
        __shared__ float2 m1w[2][NP];
        __shared__ __align__(16) float2 t1s[2][NP];
        const float2* M1 = (const float2*)(ws + OFF_M1);
        for (int idx = tid; idx < 2 * NP; idx += 192) {
            int r = idx / NP, m = idx % NP;
            if (k0 + r < N) m1w[r][m] = M1[(k0 + r) * N + 39 + m];
        }
        __syncthreads();
        {   // T1 rows
            int grp = tid / 96, tcol = tid % 96;
            if (tcol < NP && k0 + grp < N) {
                float2 acc = {0.f, 0.f};
                for (int nr = 0; nr < NP; nr++) {
                    float2 w = m1w[grp][nr];
                    float xv = x[(bj * NP + nr) * NP + tcol];
                    acc.x += w.x * xv; acc.y += w.y * xv;
                }
                t1s[grp][tcol] = acc;
            }
        }
        __syncthreads();
        // X rows
        int col = tid % HCOL, grp = tid / HCOL;
        if (grp >= 2) return;
        int kr = k0 + grp;
        if (kr >= N) return;
        const float2* M1T = (const float2*)(ws + OFF_M1T);
        float2 acc = {0.f, 0.f};
#pragma unroll 5
        for (int ncp = 0; ncp < 45; ncp++) {
            int nc = 2 * ncp;
            float4 u = *(const float4*)&t1s[grp][nc];
            float2 w0 = M1T[(39 + nc) * N + col];
            float2 w1 = M1T[(40 + nc) * N + col];
            acc.x += u.x * w0.x - u.y * w0.y;
            acc.y += u.x * w0.y + u.y * w0.x;
            acc.x += u.z * w1.x - u.w * w1.y;
            acc.y += u.z * w1.y + u.w * w1.x;
        }
        ((float2*)(ws + OFF_X))[((size_t)bj * N + kr) * HCOL + col] = acc;
    } else {
        int c = blockIdx.y;
        if (c >= 8) return;
        __shared__ float2 wfw[2][MP];
        __shared__ __align__(16) float2 t2s[2][2][MP];
        __shared__ float bds[2][N];
        const float2* WF = (const float2*)(ws + OFF_WF);
        for (int idx = tid; idx < 2 * MP; idx += 192) {
            int r = idx / MP, m = idx % MP;
            if (k0 + r < N) wfw[r][m] = WF[(k0 + r) * N + 42 + m];
        }
        __syncthreads();
#pragma unroll
        for (int pass = 0; pass < 2; pass++) {
            int jj = (pass == 0) ? c : c + 8;
            int grp = tid / 96, tcol = tid % 96;
            if (tcol < MP && k0 + grp < N) {
                const float2* PC = (const float2*)(ws + OFF_PC) + (size_t)jj * MP * MP;
                float2 acc = {0.f, 0.f};
                for (int nr = 0; nr < MP; nr++) {
                    float2 w = wfw[grp][nr];
                    float2 pc = PC[nr * MP + tcol];
                    acc.x += w.x * pc.x - w.y * pc.y;
                    acc.y += w.x * pc.y + w.y * pc.x;
                }
                t2s[pass][grp][tcol] = acc;
            }
        }
        __syncthreads();
        if (tid < N) {
            float inv_amp = 1.0f / ws[OFF_AMP];
#pragma unroll
            for (int rr = 0; rr < 2; rr++) {
                if (k0 + rr < N) {
                    float2 a0 = {0.f, 0.f}, a1 = {0.f, 0.f};
                    for (int ncp = 0; ncp < 42; ncp++) {
                        int nc = 2 * ncp;
                        float2 w0 = WF[(42 + nc) * N + tid];
                        float2 w1 = WF[(43 + nc) * N + tid];
                        float4 u0 = *(const float4*)&t2s[0][rr][nc];
                        a0.x += u0.x * w0.x - u0.y * w0.y;
                        a0.y += u0.x * w0.y + u0.y * w0.x;
                        a0.x += u0.z * w1.x - u0.w * w1.y;
                        a0.y += u0.z * w1.y + u0.w * w1.x;
                        float4 u1 = *(const float4*)&t2s[1][rr][nc];
                        a1.x += u1.x * w0.x - u1.y * w0.y;
                        a1.y += u1.x * w0.y + u1.y * w0.x;
                        a1.x += u1.z * w1.x - u1.w * w1.y;
                        a1.y += u1.z * w1.y + u1.w * w1.x;
                    }
                    bds[rr][tid] = (a0.x * a0.x + a0.y * a0.y - a1.x * a1.x - a1.y * a1.y) * inv_amp;
                }
            }
        }
        __syncthreads();
        {
            int grp = tid / 96, col = tid % 96;
            if (col < HCOL && k0 + grp < N) {
                const float2* M2T = (const float2*)(ws + OFF_M2T);
                float2 acc = {0.f, 0.f};
                for (int m = 0; m < N; m++) {
                    float bv = bds[grp][m];
                    float2 w = M2T[m * N + col];
                    acc.x += w.x * bv; acc.y += w.y * bv;
                }
                ((float2*)(ws + OFF_T3))[((size_t)c * N + k0 + grp) * HCOL + col] = acc;
            }
        }
    }
}

// ---------------- stage 2d: OTF[i, 0..83] = sum_k M2[i,k] * T3[k,t] ----------------
__global__ __launch_bounds__(192) void k2d(float* ws) {
    int chunk = blockIdx.x, c = blockIdx.y, tid = threadIdx.x;
    int i0 = chunk * 2;
    __shared__ float2 m2s[2][N];
    const float2* M2 = (const float2*)(ws + OFF_M2);
    for (int idx = tid; idx < 2 * N; idx += 192) {
        int r = idx / N, k = idx % N;
        if (i0 + r < N) m2s[r][k] = M2[(size_t)(i0 + r) * N + k];   // coalesced
    }
    __syncthreads();
    int col = tid % HCOL, grp = tid / HCOL;
    if (grp >= 2) return;
    int i = i0 + grp;
    if (i >= N) return;
    const float2* T3 = (const float2*)(ws + OFF_T3) + (size_t)c * N * HCOL;
    float2 acc = {0.f, 0.f};
    for (int k = 0; k < N; k++) {
        float2 w = m2s[grp][k];
        float2 u = T3[k * HCOL + col];
        acc.x += u.x * w.x - u.y * w.y;
        acc.y += u.x * w.y + u.y * w.x;
    }
    ((float2*)(ws + OFF_OTF))[((size_t)c * N + i) * HCOL + col] = acc;
}

// ---------------- stage 3 fused: 12 rows/block, dbuf, KCH=12; phase-2 3r x 2j tiling ----------------
constexpr int K34R = 12;
constexpr int KCH  = 12;
constexpr int NT34 = (N + KCH - 1) / KCH;   // 14 (13 full + tail 11)

constexpr int SM_ZS   = 0;
constexpr int SM_M3C  = SM_ZS + 2 * KCH * HCOL * 2;      // 4032
constexpr int SM_PHIS = SM_M3C + 2 * KCH * K34R * 2;     // 4608
constexpr int SM_PM   = SM_PHIS + N * 2;                 // 4942
constexpr int SM_TOT  = SM_PM + 4 * CROP;                // 5422 floats = 21688 B

constexpr int ZBUF = KCH * HCOL;
constexpr int MBUF = KCH * K34R;

#define K34_FMA_BODY(kl)                                                        \
    {                                                                           \
        float4 zz = *(const float4*)&zcur[(kl) * HCOL + 2 * pair];              \
        float4 wa = *(const float4*)&mcur[(kl) * K34R + r0];                    \
        a00.x += wa.x * zz.x - wa.y * zz.y;  a00.y += wa.x * zz.y + wa.y * zz.x;\
        a01.x += wa.x * zz.z - wa.y * zz.w;  a01.y += wa.x * zz.w + wa.y * zz.z;\
        a10.x += wa.z * zz.x - wa.w * zz.y;  a10.y += wa.z * zz.y + wa.w * zz.x;\
        a11.x += wa.z * zz.z - wa.w * zz.w;  a11.y += wa.z * zz.w + wa.w * zz.z;\
    }

__global__ __launch_bounds__(256) void k34(float* ws) {
    int chunk = blockIdx.x, c = blockIdx.y, b = blockIdx.z, tid = threadIdx.x;
    int i0 = chunk * K34R;
    __shared__ __align__(16) float smem[SM_TOT];
    float2* zbase = (float2*)(smem + SM_ZS);
    float2* mbase = (float2*)(smem + SM_M3C);
    float2* phis  = (float2*)(smem + SM_PHIS);
    float*  pmf   = smem + SM_PM;
    float2 (*us)[HCOL] = (float2 (*)[HCOL])(smem + SM_ZS);   // alias: zs dead after loop

    const float2* M3 = (const float2*)(ws + OFF_M3);
    const float4* X4   = (const float4*)(ws + OFF_X   + (size_t)b * N * HCOL * 2);
    const float4* OTF4 = (const float4*)(ws + OFF_OTF + (size_t)c * N * HCOL * 2);
    for (int idx = tid; idx < N; idx += 256) phis[idx] = ((const float2*)(ws + OFF_PHI2))[idx];

    int qkl[2], qcp[2];
#pragma unroll
    for (int e = 0; e < 2; e++) {
        int idx = tid + e * 256;
        qkl[e] = idx / 42; qcp[e] = idx - qkl[e] * 42;
    }
    int mkl = tid % 12, mr = tid / 12;   // tid<144: m3c coords

    int pair = tid % 42, grp = tid / 42;
    int r0 = grp * 2;
    float2 a00 = {0.f,0.f}, a01 = {0.f,0.f}, a10 = {0.f,0.f}, a11 = {0.f,0.f};

    float4 xq[2], oq[2];
    float2 m3r;

#pragma unroll
    for (int e = 0; e < 2; e++)
        if (qkl[e] < KCH) { xq[e] = X4[qkl[e] * 42 + qcp[e]]; oq[e] = OTF4[qkl[e] * 42 + qcp[e]]; }
    if (tid < 144) m3r = M3[(i0 + mr) * N + mkl];
#pragma unroll
    for (int e = 0; e < 2; e++)
        if (qkl[e] < KCH) {
            float4 z;
            z.x = xq[e].x * oq[e].x - xq[e].y * oq[e].y;
            z.y = xq[e].x * oq[e].y + xq[e].y * oq[e].x;
            z.z = xq[e].z * oq[e].z - xq[e].w * oq[e].w;
            z.w = xq[e].z * oq[e].w + xq[e].w * oq[e].z;
            *(float4*)&zbase[qkl[e] * HCOL + 2 * qcp[e]] = z;
        }
    if (tid < 144) mbase[mkl * K34R + mr] = m3r;
    __syncthreads();

    for (int t = 0; t < NT34; t++) {
        int cbuf = t & 1, nbuf = cbuf ^ 1;
        int kr0 = t * KCH;
        int chn = min(KCH, N - kr0);
        int nbase = kr0 + KCH;
        int nchn = (t + 1 < NT34) ? (N - nbase < KCH ? N - nbase : KCH) : 0;
        if (nchn > 0) {
#pragma unroll
            for (int e = 0; e < 2; e++)
                if (qkl[e] < nchn) { xq[e] = X4[(nbase + qkl[e]) * 42 + qcp[e]];
                                     oq[e] = OTF4[(nbase + qkl[e]) * 42 + qcp[e]]; }
            if (tid < 144 && mkl < nchn) m3r = M3[(i0 + mr) * N + nbase + mkl];
        }
        const float2* zcur = zbase + cbuf * ZBUF;
        const float2* mcur = mbase + cbuf * MBUF;
        if (grp < 6) {
            if (chn == KCH) {
#pragma unroll
                for (int kl = 0; kl < KCH; kl++) K34_FMA_BODY(kl)
            } else {
#pragma unroll
                for (int kl = 0; kl < KCH - 1; kl++) K34_FMA_BODY(kl)   // tail chn = 11
            }
        }
        if (nchn > 0) {
            float2* znxt = zbase + nbuf * ZBUF;
            float2* mnxt = mbase + nbuf * MBUF;
#pragma unroll
            for (int e = 0; e < 2; e++)
                if (qkl[e] < nchn) {
                    float4 z;
                    z.x = xq[e].x * oq[e].x - xq[e].y * oq[e].y;
                    z.y = xq[e].x * oq[e].y + xq[e].y * oq[e].x;
                    z.z = xq[e].z * oq[e].z - xq[e].w * oq[e].w;
                    z.w = xq[e].z * oq[e].w + xq[e].w * oq[e].z;
                    *(float4*)&znxt[qkl[e] * HCOL + 2 * qcp[e]] = z;
                }
            if (tid < 144 && mkl < nchn) mnxt[mkl * K34R + mr] = m3r;
        }
        __syncthreads();
    }

    if (grp < 6) {
        *(float4*)&us[r0][2 * pair]     = make_float4(a00.x, a00.y, a01.x, a01.y);
        *(float4*)&us[r0 + 1][2 * pair] = make_float4(a10.x, a10.y, a11.x, a11.y);
    }
    __syncthreads();

    // ---- phase 2: 240 threads = 4 pool-row groups x 60 j-pairs; 3 rows x 2 j each ----
    if (tid < 240) {
        int g = tid / 60, jp = tid % 60;
        int rbase = g * 3;
        int j0 = 2 * jp;
        const float2* M3T84 = (const float2*)(ws + OFF_M3T84);
        float2 A[3][2]; float Bq[3][2];
#pragma unroll
        for (int q = 0; q < 3; q++) {
            A[q][0] = make_float2(0.f, 0.f);
            A[q][1] = make_float2(0.f, 0.f);
        }
#pragma unroll 4
        for (int ncp = 0; ncp < 41; ncp++) {
            int nc = 2 * ncp;
            float4 wv0 = *(const float4*)&M3T84[nc * CROP + j0];        // w(nc, j0), w(nc, j1)
            float4 wv1 = *(const float4*)&M3T84[(nc + 1) * CROP + j0];  // w(nc+1, j0), w(nc+1, j1)
#pragma unroll
            for (int q = 0; q < 3; q++) {
                float4 u = *(const float4*)&us[rbase + q][nc];          // u(nc), u(nc+1)
                A[q][0].x += u.x * wv0.x - u.y * wv0.y;
                A[q][0].y += u.x * wv0.y + u.y * wv0.x;
                A[q][0].x += u.z * wv1.x - u.w * wv1.y;
                A[q][0].y += u.z * wv1.y + u.w * wv1.x;
                A[q][1].x += u.x * wv0.z - u.y * wv0.w;
                A[q][1].y += u.x * wv0.w + u.y * wv0.z;
                A[q][1].x += u.z * wv1.z - u.w * wv1.w;
                A[q][1].y += u.z * wv1.w + u.w * wv1.z;
            }
        }
        {   // nc = 82 singleton
            float4 wv = *(const float4*)&M3T84[82 * CROP + j0];
#pragma unroll
            for (int q = 0; q < 3; q++) {
                float2 u = us[rbase + q][82];
                A[q][0].x += u.x * wv.x - u.y * wv.y;
                A[q][0].y += u.x * wv.y + u.y * wv.x;
                A[q][1].x += u.x * wv.z - u.y * wv.w;
                A[q][1].y += u.x * wv.w + u.y * wv.z;
            }
        }
        {   // B term: nc = 83 (self-paired column), real part only
            float4 wv = *(const float4*)&M3T84[(HCOL - 1) * CROP + j0];
#pragma unroll
            for (int q = 0; q < 3; q++) {
                float2 u = us[rbase + q][HCOL - 1];
                Bq[q][0] = u.x * wv.x - u.y * wv.y;
                Bq[q][1] = u.x * wv.z - u.y * wv.w;
            }
        }
#pragma unroll
        for (int jj = 0; jj < 2; jj++) {
            int j = j0 + jj;
            float vmax = 0.f;   // relu folded in
#pragma unroll
            for (int r = 0; r < 3; r++) {
                int i = i0 + rbase + r;
                int s = i + j + 49; if (s >= N) s -= N;   // (i+j+216) mod 167
                float2 ph = phis[s];
                float val = A[r][jj].x * (1.0f + ph.x) - A[r][jj].y * ph.y + Bq[r][jj];
                unsigned idx = (((unsigned)b * N + (24 + i)) * N + (24 + j)) * 8u + c;
                val += 0.003f * noise_at(idx);
                vmax = fmaxf(vmax, val);
            }
            pmf[g * CROP + j] = vmax;
        }
    }
    __syncthreads();
    if (tid < 160) {
        int pr = tid / 40, pc = tid % 40;
        float m = fmaxf(fmaxf(pmf[pr * CROP + 3 * pc], pmf[pr * CROP + 3 * pc + 1]),
                        pmf[pr * CROP + 3 * pc + 2]);
        int prow = chunk * 4 + pr;
        ws[OFF_FLAT + (size_t)b * 12800 + ((size_t)prow * 40 + pc) * 8 + c] = m;
    }
}

// ---------------- stage 4: dense(12800->10) + softmax ----------------
__global__ void k5(const float* __restrict__ W3, const float* __restrict__ b3,
                   const float* __restrict__ ws, float* __restrict__ out) {
    int b = blockIdx.x, t = threadIdx.x;
    __shared__ float red[256][10];
    float acc[10];
#pragma unroll
    for (int o = 0; o < 10; o++) acc[o] = 0.f;
    const float* fl = ws + OFF_FLAT + (size_t)b * 12800;
    for (int f = t; f < 12800; f += 256) {
        float v = fl[f];
#pragma unroll
        for (int o = 0; o < 10; o++) acc[o] = fmaf(v, W3[f * 10 + o], acc[o]);
    }
#pragma unroll
    for (int o = 0; o < 10; o++) red[t][o] = acc[o];
    __syncthreads();
    for (int s = 128; s > 0; s >>= 1) {
        if (t < s) {
#pragma unroll
            for (int o = 0; o < 10; o++) red[t][o] += red[t + s][o];
        }
        __syncthreads();
    }
    if (t == 0) {
        float lg[10], mx = -1e30f;
#pragma unroll
        for (int o = 0; o < 10; o++) { lg[o] = red[0][o] + b3[o]; mx = fmaxf(mx, lg[o]); }
        float sum = 0.f;
#pragma unroll
        for (int o = 0; o < 10; o++) { lg[o] = expf(lg[o] - mx); sum += lg[o]; }
#pragma unroll
        for (int o = 0; o < 10; o++) out[b * 10 + o] = lg[o] / sum;
    }
}

extern "C" void kernel_launch(void* const* d_in, const int* in_sizes, int n_in,
                              void* d_out, int out_size, void* d_ws, size_t ws_size,
                              hipStream_t stream) {
    const float* x  = (const float*)d_in[0];   // [16,90,90,1]
    const float* P  = (const float*)d_in[1];   // [16,84,84]
    const float* W3 = (const float*)d_in[2];   // [12800,10]
    const float* b3 = (const float*)d_in[3];   // [10]
    float* ws  = (float*)d_ws;
    float* out = (float*)d_out;                // [16,10]

    k_prep<<<700, 256, 0, stream>>>(P, ws);
    k_s1<<<dim3(84, 16, 2), 192, 0, stream>>>(x, ws);
    k2d<<<dim3(84, 8), 192, 0, stream>>>(ws);
    k34<<<dim3(CROP / K34R, 8, 16), 256, 0, stream>>>(ws);
    k5<<<16, 256, 0, stream>>>(W3, b3, ws, out);
}